// Round 1
// baseline (6464.687 us; speedup 1.0000x reference)
//
#include <hip/hip_runtime.h>
#include <math.h>

// ---------------------------------------------------------------------------
// IntraModalContrastive loss, fp32 baseline.
// Pipeline per modality m:
//   bufA = feat @ Wa + ba                     (8192 x 1024)
//   bufB = relu(bufA @ W1 + b1)               (8192 x 1024)
//   bufC = normalize(bufB @ W2 + b2)          (8192 x 512)   modal_proj
//   bufA = relu(id @ W1 + b1)                 (8192 x 1024)
//   bufD = normalize(bufA @ W2 + b2)          (8192 x 512)   id_proj
//   for 8 chunks of 1024 rows:
//     bufS = 10 * id_proj[chunk] @ modal_proj^T   (1024 x 8192)
//     row_loss: radix-select 4096th largest of ranking, weights, logsumexp,
//               atomicAdd ce*mw into accum[m]
// out[0] = (accum[0]+accum[1]) / 16384
// ---------------------------------------------------------------------------

#define B_ROWS 8192
#define CHUNK  1024

// ---------- GEMM NN: C[M,N] = act(A[M,K] @ W[K,N] + bias[N]) ----------------
// M,N multiples of 64; K multiple of 16.
__global__ __launch_bounds__(256) void gemm_nn_kernel(
    const float* __restrict__ A, const float* __restrict__ W,
    const float* __restrict__ bias, float* __restrict__ C,
    int M, int N, int K, int do_relu)
{
    __shared__ float As[64][17];   // [m][k], padded
    __shared__ float Bs[16][64];   // [k][n], float4-friendly

    const int t  = threadIdx.x;
    const int tx = t & 15;         // col group (4 cols each)
    const int ty = t >> 4;         // row group (4 rows each)
    const int n0 = blockIdx.x * 64;
    const int m0 = blockIdx.y * 64;

    const int a_row = t >> 2;            // 0..63
    const int a_kc  = (t & 3) << 2;      // 0,4,8,12
    const int b_k   = t >> 4;            // 0..15
    const int b_nc  = (t & 15) << 2;     // 0..60

    float acc[4][4];
#pragma unroll
    for (int r = 0; r < 4; ++r)
#pragma unroll
        for (int c = 0; c < 4; ++c) acc[r][c] = 0.0f;

    for (int k0 = 0; k0 < K; k0 += 16) {
        float4 av = *(const float4*)(A + (size_t)(m0 + a_row) * K + (k0 + a_kc));
        As[a_row][a_kc + 0] = av.x;
        As[a_row][a_kc + 1] = av.y;
        As[a_row][a_kc + 2] = av.z;
        As[a_row][a_kc + 3] = av.w;
        float4 wv = *(const float4*)(W + (size_t)(k0 + b_k) * N + (n0 + b_nc));
        *(float4*)(&Bs[b_k][b_nc]) = wv;
        __syncthreads();
#pragma unroll
        for (int k = 0; k < 16; ++k) {
            float a0 = As[ty * 4 + 0][k];
            float a1 = As[ty * 4 + 1][k];
            float a2 = As[ty * 4 + 2][k];
            float a3 = As[ty * 4 + 3][k];
            float4 b = *(const float4*)(&Bs[k][tx * 4]);
            acc[0][0] = fmaf(a0, b.x, acc[0][0]);
            acc[0][1] = fmaf(a0, b.y, acc[0][1]);
            acc[0][2] = fmaf(a0, b.z, acc[0][2]);
            acc[0][3] = fmaf(a0, b.w, acc[0][3]);
            acc[1][0] = fmaf(a1, b.x, acc[1][0]);
            acc[1][1] = fmaf(a1, b.y, acc[1][1]);
            acc[1][2] = fmaf(a1, b.z, acc[1][2]);
            acc[1][3] = fmaf(a1, b.w, acc[1][3]);
            acc[2][0] = fmaf(a2, b.x, acc[2][0]);
            acc[2][1] = fmaf(a2, b.y, acc[2][1]);
            acc[2][2] = fmaf(a2, b.z, acc[2][2]);
            acc[2][3] = fmaf(a2, b.w, acc[2][3]);
            acc[3][0] = fmaf(a3, b.x, acc[3][0]);
            acc[3][1] = fmaf(a3, b.y, acc[3][1]);
            acc[3][2] = fmaf(a3, b.z, acc[3][2]);
            acc[3][3] = fmaf(a3, b.w, acc[3][3]);
        }
        __syncthreads();
    }

    float4 b4 = *(const float4*)(bias + n0 + tx * 4);
#pragma unroll
    for (int r = 0; r < 4; ++r) {
        float4 o;
        o.x = acc[r][0] + b4.x;
        o.y = acc[r][1] + b4.y;
        o.z = acc[r][2] + b4.z;
        o.w = acc[r][3] + b4.w;
        if (do_relu) {
            o.x = fmaxf(o.x, 0.0f);
            o.y = fmaxf(o.y, 0.0f);
            o.z = fmaxf(o.z, 0.0f);
            o.w = fmaxf(o.w, 0.0f);
        }
        *(float4*)(C + (size_t)(m0 + ty * 4 + r) * N + (n0 + tx * 4)) = o;
    }
}

// ---------- GEMM NT: C[M,N] = scale * A[M,K] @ B[N,K]^T ---------------------
__global__ __launch_bounds__(256) void gemm_nt_kernel(
    const float* __restrict__ A, const float* __restrict__ B,
    float* __restrict__ C, int M, int N, int K, float scale)
{
    __shared__ float As[64][17];   // [m][k]
    __shared__ float Bs[64][17];   // [n][k]

    const int t  = threadIdx.x;
    const int tx = t & 15;
    const int ty = t >> 4;
    const int n0 = blockIdx.x * 64;
    const int m0 = blockIdx.y * 64;

    const int l_row = t >> 2;          // 0..63
    const int l_kc  = (t & 3) << 2;    // 0,4,8,12

    float acc[4][4];
#pragma unroll
    for (int r = 0; r < 4; ++r)
#pragma unroll
        for (int c = 0; c < 4; ++c) acc[r][c] = 0.0f;

    for (int k0 = 0; k0 < K; k0 += 16) {
        float4 av = *(const float4*)(A + (size_t)(m0 + l_row) * K + (k0 + l_kc));
        As[l_row][l_kc + 0] = av.x;
        As[l_row][l_kc + 1] = av.y;
        As[l_row][l_kc + 2] = av.z;
        As[l_row][l_kc + 3] = av.w;
        float4 bv = *(const float4*)(B + (size_t)(n0 + l_row) * K + (k0 + l_kc));
        Bs[l_row][l_kc + 0] = bv.x;
        Bs[l_row][l_kc + 1] = bv.y;
        Bs[l_row][l_kc + 2] = bv.z;
        Bs[l_row][l_kc + 3] = bv.w;
        __syncthreads();
#pragma unroll
        for (int k = 0; k < 16; ++k) {
            float a0 = As[ty * 4 + 0][k];
            float a1 = As[ty * 4 + 1][k];
            float a2 = As[ty * 4 + 2][k];
            float a3 = As[ty * 4 + 3][k];
            float b0 = Bs[tx * 4 + 0][k];
            float b1 = Bs[tx * 4 + 1][k];
            float b2 = Bs[tx * 4 + 2][k];
            float b3 = Bs[tx * 4 + 3][k];
            acc[0][0] = fmaf(a0, b0, acc[0][0]);
            acc[0][1] = fmaf(a0, b1, acc[0][1]);
            acc[0][2] = fmaf(a0, b2, acc[0][2]);
            acc[0][3] = fmaf(a0, b3, acc[0][3]);
            acc[1][0] = fmaf(a1, b0, acc[1][0]);
            acc[1][1] = fmaf(a1, b1, acc[1][1]);
            acc[1][2] = fmaf(a1, b2, acc[1][2]);
            acc[1][3] = fmaf(a1, b3, acc[1][3]);
            acc[2][0] = fmaf(a2, b0, acc[2][0]);
            acc[2][1] = fmaf(a2, b1, acc[2][1]);
            acc[2][2] = fmaf(a2, b2, acc[2][2]);
            acc[2][3] = fmaf(a2, b3, acc[2][3]);
            acc[3][0] = fmaf(a3, b0, acc[3][0]);
            acc[3][1] = fmaf(a3, b1, acc[3][1]);
            acc[3][2] = fmaf(a3, b2, acc[3][2]);
            acc[3][3] = fmaf(a3, b3, acc[3][3]);
        }
        __syncthreads();
    }

#pragma unroll
    for (int r = 0; r < 4; ++r) {
        float4 o;
        o.x = acc[r][0] * scale;
        o.y = acc[r][1] * scale;
        o.z = acc[r][2] * scale;
        o.w = acc[r][3] * scale;
        *(float4*)(C + (size_t)(m0 + ty * 4 + r) * N + (n0 + tx * 4)) = o;
    }
}

// ---------- row L2-normalize, width 512 -------------------------------------
__global__ __launch_bounds__(128) void normalize_kernel(float* __restrict__ X)
{
    const int r = blockIdx.x;
    const int t = threadIdx.x;
    float* row = X + (size_t)r * 512;
    float4 v = *(const float4*)(row + t * 4);
    float ss = v.x * v.x + v.y * v.y + v.z * v.z + v.w * v.w;
#pragma unroll
    for (int off = 32; off > 0; off >>= 1) ss += __shfl_down(ss, off, 64);
    __shared__ float sred[2];
    if ((t & 63) == 0) sred[t >> 6] = ss;
    __syncthreads();
    float inv = 1.0f / sqrtf(sred[0] + sred[1]);
    v.x *= inv; v.y *= inv; v.z *= inv; v.w *= inv;
    *(float4*)(row + t * 4) = v;
}

// ---------- per-row mining + loss -------------------------------------------
// One block (256 threads) per row. Row of 8192 scaled sims in LDS.
// ranking key: 0 if excluded (diag or noise), else monotonic uint of float.
__device__ __forceinline__ unsigned fkey(float s)
{
    unsigned u = __float_as_uint(s);
    return (u & 0x80000000u) ? ~u : (u | 0x80000000u);
}

__global__ __launch_bounds__(256) void row_loss_kernel(
    const float* __restrict__ S, int row_base,
    const float* __restrict__ mw, int midx, float* __restrict__ accum)
{
    __shared__ float row[8192];
    __shared__ unsigned hist[256];
    __shared__ unsigned sh_prefix, sh_target;
    __shared__ float red[4];
    __shared__ float sh_diag, sh_bmax;

    const int t = threadIdx.x;
    const int i = row_base + blockIdx.x;            // global row = diag column
    const float* Srow = S + (size_t)blockIdx.x * 8192;

    for (int j = t * 4; j < 8192; j += 1024)
        *(float4*)(&row[j]) = *(const float4*)(&Srow[j]);
    __syncthreads();

    // --- radix select: key of the 4096-th largest ranking value ---
    unsigned target = 4096;
    unsigned prefix = 0;
    for (int pass = 0; pass < 4; ++pass) {
        const int shift = 24 - pass * 8;
        hist[t] = 0;
        __syncthreads();
        for (int j = t; j < 8192; j += 256) {
            float s = row[j];
            unsigned key = (j == i || s > 9.0f) ? 0u : fkey(s);
            if (pass == 0 || (key >> (shift + 8)) == prefix)
                atomicAdd(&hist[(key >> shift) & 255u], 1u);
        }
        __syncthreads();
        if (t == 0) {
            unsigned cum = 0;
            int chosen = 0;
            for (int b = 255; b >= 0; --b) {
                unsigned c = hist[b];
                if (cum + c >= target) { chosen = b; break; }
                cum += c;
            }
            sh_prefix = (prefix << 8) | (unsigned)chosen;
            sh_target = target - cum;
        }
        __syncthreads();
        prefix = sh_prefix;
        target = sh_target;
        __syncthreads();
    }
    const unsigned tkey = prefix;

    // --- apply weights, find max ---
    float lmax = -INFINITY;
    for (int j = t; j < 8192; j += 256) {
        float s = row[j];
        bool diag  = (j == i);
        bool noise = (!diag && s > 9.0f);
        unsigned key = (diag || noise) ? 0u : fkey(s);
        float w = noise ? 0.5f : ((!diag && key >= tkey) ? 1.5f : 1.0f);
        float ws = s * w;
        row[j] = ws;
        if (diag) sh_diag = ws;
        lmax = fmaxf(lmax, ws);
    }
#pragma unroll
    for (int off = 32; off > 0; off >>= 1)
        lmax = fmaxf(lmax, __shfl_down(lmax, off, 64));
    if ((t & 63) == 0) red[t >> 6] = lmax;
    __syncthreads();
    if (t == 0) {
        sh_bmax = fmaxf(fmaxf(red[0], red[1]), fmaxf(red[2], red[3]));
    }
    __syncthreads();
    const float bmax = sh_bmax;
    __syncthreads();

    // --- sum exp ---
    float lsum = 0.0f;
    for (int j = t; j < 8192; j += 256)
        lsum += __expf(row[j] - bmax);
#pragma unroll
    for (int off = 32; off > 0; off >>= 1)
        lsum += __shfl_down(lsum, off, 64);
    if ((t & 63) == 0) red[t >> 6] = lsum;
    __syncthreads();
    if (t == 0) {
        float total = red[0] + red[1] + red[2] + red[3];
        float lse = bmax + logf(total);
        float ce = lse - sh_diag;
        atomicAdd(&accum[midx], ce * mw[(size_t)i * 2 + midx]);
    }
}

__global__ void zero_kernel(float* __restrict__ accum)
{
    if (threadIdx.x < 2) accum[threadIdx.x] = 0.0f;
}

__global__ void finalize_kernel(const float* __restrict__ accum,
                                float* __restrict__ out)
{
    out[0] = (accum[0] + accum[1]) * (1.0f / 16384.0f);
}

// ---------------------------------------------------------------------------
extern "C" void kernel_launch(void* const* d_in, const int* in_sizes, int n_in,
                              void* d_out, int out_size, void* d_ws, size_t ws_size,
                              hipStream_t stream)
{
    (void)in_sizes; (void)n_in; (void)out_size; (void)ws_size;

    const float* id_emb = (const float*)d_in[0];
    const float* feats[2] = { (const float*)d_in[1], (const float*)d_in[2] };
    const float* mw     = (const float*)d_in[3];
    const float* Wa[2]  = { (const float*)d_in[4],  (const float*)d_in[6]  };
    const float* ba[2]  = { (const float*)d_in[5],  (const float*)d_in[7]  };
    const float* W1[2]  = { (const float*)d_in[8],  (const float*)d_in[12] };
    const float* b1[2]  = { (const float*)d_in[9],  (const float*)d_in[13] };
    const float* W2[2]  = { (const float*)d_in[10], (const float*)d_in[14] };
    const float* b2[2]  = { (const float*)d_in[11], (const float*)d_in[15] };
    const int    Fdim[2] = { 768, 2048 };

    float* bufA  = (float*)d_ws;                       // 8192 x 1024
    float* bufB  = bufA + (size_t)B_ROWS * 1024;       // 8192 x 1024
    float* bufC  = bufB + (size_t)B_ROWS * 1024;       // 8192 x 512  modal_proj
    float* bufD  = bufC + (size_t)B_ROWS * 512;        // 8192 x 512  id_proj
    float* bufS  = bufD + (size_t)B_ROWS * 512;        // 1024 x 8192 sim chunk
    float* accum = bufS + (size_t)CHUNK * 8192;        // 2 floats

    zero_kernel<<<1, 64, 0, stream>>>(accum);

    for (int m = 0; m < 2; ++m) {
        // adapter: bufA = feat @ Wa + ba
        gemm_nn_kernel<<<dim3(1024 / 64, B_ROWS / 64), 256, 0, stream>>>(
            feats[m], Wa[m], ba[m], bufA, B_ROWS, 1024, Fdim[m], 0);
        // bufB = relu(bufA @ W1 + b1)
        gemm_nn_kernel<<<dim3(1024 / 64, B_ROWS / 64), 256, 0, stream>>>(
            bufA, W1[m], b1[m], bufB, B_ROWS, 1024, 1024, 1);
        // bufC = bufB @ W2 + b2
        gemm_nn_kernel<<<dim3(512 / 64, B_ROWS / 64), 256, 0, stream>>>(
            bufB, W2[m], b2[m], bufC, B_ROWS, 512, 1024, 0);
        normalize_kernel<<<B_ROWS, 128, 0, stream>>>(bufC);
        // bufA = relu(id_emb @ W1 + b1)
        gemm_nn_kernel<<<dim3(1024 / 64, B_ROWS / 64), 256, 0, stream>>>(
            id_emb, W1[m], b1[m], bufA, B_ROWS, 1024, 1024, 1);
        // bufD = bufA @ W2 + b2
        gemm_nn_kernel<<<dim3(512 / 64, B_ROWS / 64), 256, 0, stream>>>(
            bufA, W2[m], b2[m], bufD, B_ROWS, 512, 1024, 0);
        normalize_kernel<<<B_ROWS, 128, 0, stream>>>(bufD);

        for (int c = 0; c < B_ROWS / CHUNK; ++c) {
            gemm_nt_kernel<<<dim3(B_ROWS / 64, CHUNK / 64), 256, 0, stream>>>(
                bufD + (size_t)c * CHUNK * 512, bufC, bufS,
                CHUNK, B_ROWS, 512, 10.0f);
            row_loss_kernel<<<CHUNK, 256, 0, stream>>>(
                bufS, c * CHUNK, mw, m, accum);
        }
    }

    finalize_kernel<<<1, 1, 0, stream>>>(accum, (float*)d_out);
}

// Round 2
// 2304.533 us; speedup vs baseline: 2.8052x; 2.8052x over previous
//
#include <hip/hip_runtime.h>
#include <math.h>
#include <stdint.h>

// ---------------------------------------------------------------------------
// IntraModalContrastive loss. Round 1: all GEMMs via bf16 MFMA (16x16x32),
// 128x128 tiles, global_load_lds(16B) staging. fp32 accumulate everywhere.
// ---------------------------------------------------------------------------

#define B_ROWS 8192
#define CHUNK  1024

typedef __attribute__((ext_vector_type(4))) float  floatx4;
typedef __attribute__((ext_vector_type(8))) __bf16 bf16x8;

__device__ __forceinline__ unsigned short f2bf(float f)
{
    unsigned u = __float_as_uint(f);
    unsigned r = (u + 0x7FFFu + ((u >> 16) & 1u)) >> 16;
    return (unsigned short)r;
}

__device__ __forceinline__ void gld_lds16(const void* g, void* l)
{
    __builtin_amdgcn_global_load_lds(
        (const __attribute__((address_space(1))) void*)g,
        (__attribute__((address_space(3))) void*)(uint32_t)(uintptr_t)l,
        16, 0, 0);
}

// ---------- bf16 MFMA GEMM: C[M,N] = ep(scale*(A @ B^T) + bias) -------------
// A: M x K bf16 row-major (lda), B: N x K bf16 row-major (ldb).
// Tile 128x128, BK=32, 256 threads = 4 waves (2x2 of 64x64).
__global__ __launch_bounds__(256) void gemm_bt_mfma(
    const unsigned short* __restrict__ A, int lda,
    const unsigned short* __restrict__ B, int ldb,
    void* __restrict__ C, int ldc, int K,
    const float* __restrict__ bias, int relu, float scale, int out_bf16)
{
    __shared__ __align__(16) unsigned short As[128 * 32];
    __shared__ __align__(16) unsigned short Bs[128 * 32];

    const int t    = threadIdx.x;
    const int lane = t & 63;
    const int w    = t >> 6;
    const int wr   = w >> 1;        // wave row (0..1)
    const int wc   = w & 1;         // wave col (0..1)
    const size_t m0 = (size_t)blockIdx.y * 128;
    const size_t n0 = (size_t)blockIdx.x * 128;

    floatx4 acc[4][4] = {};

    const unsigned short* Abase = A + m0 * (size_t)lda;
    const unsigned short* Bbase = B + n0 * (size_t)ldb;

    const int s_row = t >> 2;            // 0..63 (issue adds +64)
    const int s_kof = (t & 3) << 3;      // 0,8,16,24

    for (int k0 = 0; k0 < K; k0 += 32) {
#pragma unroll
        for (int it = 0; it < 2; ++it) {
            const int idx = it * 256 + t;
            const int row = it * 64 + s_row;
            gld_lds16(Abase + (size_t)row * lda + k0 + s_kof, As + idx * 8);
            gld_lds16(Bbase + (size_t)row * ldb + k0 + s_kof, Bs + idx * 8);
        }
        __syncthreads();

        bf16x8 af[4], bf[4];
#pragma unroll
        for (int i = 0; i < 4; ++i) {
            af[i] = *(const bf16x8*)(As + ((wr * 64 + i * 16 + (lane & 15)) * 32 + (lane >> 4) * 8));
            bf[i] = *(const bf16x8*)(Bs + ((wc * 64 + i * 16 + (lane & 15)) * 32 + (lane >> 4) * 8));
        }
#pragma unroll
        for (int i = 0; i < 4; ++i)
#pragma unroll
            for (int j = 0; j < 4; ++j)
                acc[i][j] = __builtin_amdgcn_mfma_f32_16x16x32_bf16(
                    af[i], bf[j], acc[i][j], 0, 0, 0);
        __syncthreads();
    }

    // epilogue: D[row=(lane>>4)*4+r][col=lane&15] per 16x16 tile
    const int col   = lane & 15;
    const int rquad = (lane >> 4) * 4;
#pragma unroll
    for (int j = 0; j < 4; ++j) {
        const size_t gc = n0 + wc * 64 + j * 16 + col;
        const float bv = bias ? bias[gc] : 0.0f;
#pragma unroll
        for (int i = 0; i < 4; ++i) {
            const size_t gr0 = m0 + wr * 64 + i * 16 + rquad;
#pragma unroll
            for (int r = 0; r < 4; ++r) {
                float v = acc[i][j][r] * scale + bv;
                if (relu) v = fmaxf(v, 0.0f);
                if (out_bf16)
                    ((unsigned short*)C)[(gr0 + r) * (size_t)ldc + gc] = f2bf(v);
                else
                    ((float*)C)[(gr0 + r) * (size_t)ldc + gc] = v;
            }
        }
    }
}

// ---------- elementwise fp32 -> bf16 cast -----------------------------------
__global__ __launch_bounds__(256) void cast_bf16_kernel(
    const float* __restrict__ in, unsigned short* __restrict__ out, int n4)
{
    const int i = blockIdx.x * 256 + threadIdx.x;
    if (i < n4) {
        float4 v = *(const float4*)(in + (size_t)i * 4);
        ushort4 o;
        o.x = f2bf(v.x); o.y = f2bf(v.y); o.z = f2bf(v.z); o.w = f2bf(v.w);
        *(ushort4*)(out + (size_t)i * 4) = o;
    }
}

// ---------- transpose + cast: W[K,N] fp32 -> WT[N,K] bf16 -------------------
__global__ __launch_bounds__(256) void transpose_cast_kernel(
    const float* __restrict__ W, unsigned short* __restrict__ WT, int K, int N)
{
    __shared__ float tile[32][33];
    const int k0 = blockIdx.y * 32;
    const int n0 = blockIdx.x * 32;
    const int tr = threadIdx.x >> 3;         // 0..31
    const int tc = (threadIdx.x & 7) * 4;    // 0..28

    float4 v = *(const float4*)(W + (size_t)(k0 + tr) * N + n0 + tc);
    tile[tr][tc + 0] = v.x;
    tile[tr][tc + 1] = v.y;
    tile[tr][tc + 2] = v.z;
    tile[tr][tc + 3] = v.w;
    __syncthreads();

    ushort4 o;
    o.x = f2bf(tile[tc + 0][tr]);
    o.y = f2bf(tile[tc + 1][tr]);
    o.z = f2bf(tile[tc + 2][tr]);
    o.w = f2bf(tile[tc + 3][tr]);
    *(ushort4*)(WT + (size_t)(n0 + tr) * K + k0 + tc) = o;
}

// ---------- row L2-normalize fp32 -> bf16, width 512 ------------------------
__global__ __launch_bounds__(128) void normalize_cast_kernel(
    const float* __restrict__ X, unsigned short* __restrict__ Y)
{
    const int r = blockIdx.x;
    const int t = threadIdx.x;
    const float* row = X + (size_t)r * 512;
    float4 v = *(const float4*)(row + t * 4);
    float ss = v.x * v.x + v.y * v.y + v.z * v.z + v.w * v.w;
#pragma unroll
    for (int off = 32; off > 0; off >>= 1) ss += __shfl_down(ss, off, 64);
    __shared__ float sred[2];
    if ((t & 63) == 0) sred[t >> 6] = ss;
    __syncthreads();
    float inv = 1.0f / sqrtf(sred[0] + sred[1]);
    ushort4 o;
    o.x = f2bf(v.x * inv); o.y = f2bf(v.y * inv);
    o.z = f2bf(v.z * inv); o.w = f2bf(v.w * inv);
    *(ushort4*)(Y + (size_t)r * 512 + t * 4) = o;
}

// ---------- per-row mining + loss -------------------------------------------
__device__ __forceinline__ unsigned fkey(float s)
{
    unsigned u = __float_as_uint(s);
    return (u & 0x80000000u) ? ~u : (u | 0x80000000u);
}

__global__ __launch_bounds__(256) void row_loss_kernel(
    const float* __restrict__ S, int row_base,
    const float* __restrict__ mw, int midx, float* __restrict__ accum)
{
    __shared__ float row[8192];
    __shared__ unsigned hist[256];
    __shared__ unsigned sh_prefix, sh_target;
    __shared__ float red[4];
    __shared__ float sh_diag, sh_bmax;

    const int t = threadIdx.x;
    const int i = row_base + blockIdx.x;
    const float* Srow = S + (size_t)blockIdx.x * 8192;

    for (int j = t * 4; j < 8192; j += 1024)
        *(float4*)(&row[j]) = *(const float4*)(&Srow[j]);
    __syncthreads();

    unsigned target = 4096;
    unsigned prefix = 0;
    for (int pass = 0; pass < 4; ++pass) {
        const int shift = 24 - pass * 8;
        hist[t] = 0;
        __syncthreads();
        for (int j = t; j < 8192; j += 256) {
            float s = row[j];
            unsigned key = (j == i || s > 9.0f) ? 0u : fkey(s);
            if (pass == 0 || (key >> (shift + 8)) == prefix)
                atomicAdd(&hist[(key >> shift) & 255u], 1u);
        }
        __syncthreads();
        if (t == 0) {
            unsigned cum = 0;
            int chosen = 0;
            for (int b = 255; b >= 0; --b) {
                unsigned c = hist[b];
                if (cum + c >= target) { chosen = b; break; }
                cum += c;
            }
            sh_prefix = (prefix << 8) | (unsigned)chosen;
            sh_target = target - cum;
        }
        __syncthreads();
        prefix = sh_prefix;
        target = sh_target;
        __syncthreads();
    }
    const unsigned tkey = prefix;

    float lmax = -INFINITY;
    for (int j = t; j < 8192; j += 256) {
        float s = row[j];
        bool diag  = (j == i);
        bool noise = (!diag && s > 9.0f);
        unsigned key = (diag || noise) ? 0u : fkey(s);
        float wgt = noise ? 0.5f : ((!diag && key >= tkey) ? 1.5f : 1.0f);
        float ws = s * wgt;
        row[j] = ws;
        if (diag) sh_diag = ws;
        lmax = fmaxf(lmax, ws);
    }
#pragma unroll
    for (int off = 32; off > 0; off >>= 1)
        lmax = fmaxf(lmax, __shfl_down(lmax, off, 64));
    if ((t & 63) == 0) red[t >> 6] = lmax;
    __syncthreads();
    if (t == 0)
        sh_bmax = fmaxf(fmaxf(red[0], red[1]), fmaxf(red[2], red[3]));
    __syncthreads();
    const float bmax = sh_bmax;
    __syncthreads();

    float lsum = 0.0f;
    for (int j = t; j < 8192; j += 256)
        lsum += __expf(row[j] - bmax);
#pragma unroll
    for (int off = 32; off > 0; off >>= 1)
        lsum += __shfl_down(lsum, off, 64);
    if ((t & 63) == 0) red[t >> 6] = lsum;
    __syncthreads();
    if (t == 0) {
        float total = red[0] + red[1] + red[2] + red[3];
        float lse = bmax + logf(total);
        float ce = lse - sh_diag;
        atomicAdd(&accum[midx], ce * mw[(size_t)i * 2 + midx]);
    }
}

__global__ void zero_kernel(float* __restrict__ accum)
{
    if (threadIdx.x < 2) accum[threadIdx.x] = 0.0f;
}

__global__ void finalize_kernel(const float* __restrict__ accum,
                                float* __restrict__ out)
{
    out[0] = (accum[0] + accum[1]) * (1.0f / 16384.0f);
}

// ---------------------------------------------------------------------------
extern "C" void kernel_launch(void* const* d_in, const int* in_sizes, int n_in,
                              void* d_out, int out_size, void* d_ws, size_t ws_size,
                              hipStream_t stream)
{
    (void)in_sizes; (void)n_in; (void)out_size; (void)ws_size;

    const float* id_emb = (const float*)d_in[0];
    const float* feats[2] = { (const float*)d_in[1], (const float*)d_in[2] };
    const float* mw     = (const float*)d_in[3];
    const float* Wa[2]  = { (const float*)d_in[4],  (const float*)d_in[6]  };
    const float* ba[2]  = { (const float*)d_in[5],  (const float*)d_in[7]  };
    const float* W1[2]  = { (const float*)d_in[8],  (const float*)d_in[12] };
    const float* b1[2]  = { (const float*)d_in[9],  (const float*)d_in[13] };
    const float* W2[2]  = { (const float*)d_in[10], (const float*)d_in[14] };
    const float* b2[2]  = { (const float*)d_in[11], (const float*)d_in[15] };
    const int    Fdim[2] = { 768, 2048 };

    char* p = (char*)d_ws;
    unsigned short* idb   = (unsigned short*)p; p += (size_t)8192 * 1024 * 2; // 16 MB
    unsigned short* R1    = (unsigned short*)p; p += (size_t)8192 * 2048 * 2; // 32 MB (featb / h2)
    unsigned short* WaT   = (unsigned short*)p; p += (size_t)1024 * 2048 * 2; //  4 MB
    unsigned short* W1T   = (unsigned short*)p; p += (size_t)1024 * 1024 * 2; //  2 MB
    unsigned short* W2T   = (unsigned short*)p; p += (size_t)512  * 1024 * 2; //  1 MB
    unsigned short* h1    = (unsigned short*)p; p += (size_t)8192 * 1024 * 2; // 16 MB
    unsigned short* mproj = (unsigned short*)p; p += (size_t)8192 * 512  * 2; //  8 MB
    unsigned short* iproj = (unsigned short*)p; p += (size_t)8192 * 512  * 2; //  8 MB
    float*          S     = (float*)p;          p += (size_t)CHUNK * 8192 * 4;// 32 MB
    float*          projf = (float*)S;          // alias: 16 MB, used before S
    float*          accum = (float*)p;

    zero_kernel<<<1, 64, 0, stream>>>(accum);

    // id embeddings -> bf16 (used by both modalities)
    cast_bf16_kernel<<<(8192 * 1024 / 4 + 255) / 256, 256, 0, stream>>>(
        id_emb, idb, 8192 * 1024 / 4);

    for (int m = 0; m < 2; ++m) {
        const int F = Fdim[m];
        unsigned short* featb = R1;
        unsigned short* h2    = R1;   // reuse after featb consumed

        cast_bf16_kernel<<<(8192 * F / 4 + 255) / 256, 256, 0, stream>>>(
            feats[m], featb, 8192 * F / 4);
        transpose_cast_kernel<<<dim3(1024 / 32, F / 32), 256, 0, stream>>>(
            Wa[m], WaT, F, 1024);
        transpose_cast_kernel<<<dim3(1024 / 32, 1024 / 32), 256, 0, stream>>>(
            W1[m], W1T, 1024, 1024);
        transpose_cast_kernel<<<dim3(512 / 32, 1024 / 32), 256, 0, stream>>>(
            W2[m], W2T, 1024, 512);

        // h1 = feat @ Wa + ba            (8192 x 1024, bf16)
        gemm_bt_mfma<<<dim3(1024 / 128, 8192 / 128), 256, 0, stream>>>(
            featb, F, WaT, F, h1, 1024, F, ba[m], 0, 1.0f, 1);
        // h2 = relu(h1 @ W1 + b1)        (8192 x 1024, bf16)
        gemm_bt_mfma<<<dim3(1024 / 128, 8192 / 128), 256, 0, stream>>>(
            h1, 1024, W1T, 1024, h2, 1024, 1024, b1[m], 1, 1.0f, 1);
        // projf = h2 @ W2 + b2           (8192 x 512, fp32)
        gemm_bt_mfma<<<dim3(512 / 128, 8192 / 128), 256, 0, stream>>>(
            h2, 1024, W2T, 1024, projf, 512, 1024, b2[m], 0, 1.0f, 0);
        normalize_cast_kernel<<<8192, 128, 0, stream>>>(projf, mproj);

        // h1 = relu(id @ W1 + b1)        (8192 x 1024, bf16)
        gemm_bt_mfma<<<dim3(1024 / 128, 8192 / 128), 256, 0, stream>>>(
            idb, 1024, W1T, 1024, h1, 1024, 1024, b1[m], 1, 1.0f, 1);
        // projf = h1 @ W2 + b2           (8192 x 512, fp32)
        gemm_bt_mfma<<<dim3(512 / 128, 8192 / 128), 256, 0, stream>>>(
            h1, 1024, W2T, 1024, projf, 512, 1024, b2[m], 0, 1.0f, 0);
        normalize_cast_kernel<<<8192, 128, 0, stream>>>(projf, iproj);

        for (int c = 0; c < B_ROWS / CHUNK; ++c) {
            // S = 10 * id_proj[chunk] @ modal_proj^T   (1024 x 8192, fp32)
            gemm_bt_mfma<<<dim3(8192 / 128, CHUNK / 128), 256, 0, stream>>>(
                iproj + (size_t)c * CHUNK * 512, 512, mproj, 512,
                S, 8192, 512, nullptr, 0, 10.0f, 0);
            row_loss_kernel<<<CHUNK, 256, 0, stream>>>(
                S, c * CHUNK, mw, m, accum);
        }
    }

    finalize_kernel<<<1, 1, 0, stream>>>(accum, (float*)d_out);
}

// Round 3
// 1459.502 us; speedup vs baseline: 4.4294x; 1.5790x over previous
//
#include <hip/hip_runtime.h>
#include <math.h>
#include <stdint.h>

// ---------------------------------------------------------------------------
// IntraModalContrastive loss. Round 2: row_loss rewritten — linear 22-bit
// fixed-point key, 2x11-bit radix select, parallel suffix scan, 512 threads.
// GEMMs: bf16 MFMA (16x16x32), 128x128 tiles, global_load_lds(16B).
// ---------------------------------------------------------------------------

#define B_ROWS 8192
#define CHUNK  1024

typedef __attribute__((ext_vector_type(4))) float  floatx4;
typedef __attribute__((ext_vector_type(8))) __bf16 bf16x8;

__device__ __forceinline__ unsigned short f2bf(float f)
{
    unsigned u = __float_as_uint(f);
    unsigned r = (u + 0x7FFFu + ((u >> 16) & 1u)) >> 16;
    return (unsigned short)r;
}

__device__ __forceinline__ void gld_lds16(const void* g, void* l)
{
    __builtin_amdgcn_global_load_lds(
        (const __attribute__((address_space(1))) void*)g,
        (__attribute__((address_space(3))) void*)(uint32_t)(uintptr_t)l,
        16, 0, 0);
}

// ---------- bf16 MFMA GEMM: C[M,N] = ep(scale*(A @ B^T) + bias) -------------
__global__ __launch_bounds__(256) void gemm_bt_mfma(
    const unsigned short* __restrict__ A, int lda,
    const unsigned short* __restrict__ B, int ldb,
    void* __restrict__ C, int ldc, int K,
    const float* __restrict__ bias, int relu, float scale, int out_bf16)
{
    __shared__ __align__(16) unsigned short As[128 * 32];
    __shared__ __align__(16) unsigned short Bs[128 * 32];

    const int t    = threadIdx.x;
    const int lane = t & 63;
    const int w    = t >> 6;
    const int wr   = w >> 1;
    const int wc   = w & 1;
    const size_t m0 = (size_t)blockIdx.y * 128;
    const size_t n0 = (size_t)blockIdx.x * 128;

    floatx4 acc[4][4] = {};

    const unsigned short* Abase = A + m0 * (size_t)lda;
    const unsigned short* Bbase = B + n0 * (size_t)ldb;

    const int s_row = t >> 2;
    const int s_kof = (t & 3) << 3;

    for (int k0 = 0; k0 < K; k0 += 32) {
#pragma unroll
        for (int it = 0; it < 2; ++it) {
            const int idx = it * 256 + t;
            const int row = it * 64 + s_row;
            gld_lds16(Abase + (size_t)row * lda + k0 + s_kof, As + idx * 8);
            gld_lds16(Bbase + (size_t)row * ldb + k0 + s_kof, Bs + idx * 8);
        }
        __syncthreads();

        bf16x8 af[4], bf[4];
#pragma unroll
        for (int i = 0; i < 4; ++i) {
            af[i] = *(const bf16x8*)(As + ((wr * 64 + i * 16 + (lane & 15)) * 32 + (lane >> 4) * 8));
            bf[i] = *(const bf16x8*)(Bs + ((wc * 64 + i * 16 + (lane & 15)) * 32 + (lane >> 4) * 8));
        }
#pragma unroll
        for (int i = 0; i < 4; ++i)
#pragma unroll
            for (int j = 0; j < 4; ++j)
                acc[i][j] = __builtin_amdgcn_mfma_f32_16x16x32_bf16(
                    af[i], bf[j], acc[i][j], 0, 0, 0);
        __syncthreads();
    }

    const int col   = lane & 15;
    const int rquad = (lane >> 4) * 4;
#pragma unroll
    for (int j = 0; j < 4; ++j) {
        const size_t gc = n0 + wc * 64 + j * 16 + col;
        const float bv = bias ? bias[gc] : 0.0f;
#pragma unroll
        for (int i = 0; i < 4; ++i) {
            const size_t gr0 = m0 + wr * 64 + i * 16 + rquad;
#pragma unroll
            for (int r = 0; r < 4; ++r) {
                float v = acc[i][j][r] * scale + bv;
                if (relu) v = fmaxf(v, 0.0f);
                if (out_bf16)
                    ((unsigned short*)C)[(gr0 + r) * (size_t)ldc + gc] = f2bf(v);
                else
                    ((float*)C)[(gr0 + r) * (size_t)ldc + gc] = v;
            }
        }
    }
}

// ---------- elementwise fp32 -> bf16 cast -----------------------------------
__global__ __launch_bounds__(256) void cast_bf16_kernel(
    const float* __restrict__ in, unsigned short* __restrict__ out, int n4)
{
    const int i = blockIdx.x * 256 + threadIdx.x;
    if (i < n4) {
        float4 v = *(const float4*)(in + (size_t)i * 4);
        ushort4 o;
        o.x = f2bf(v.x); o.y = f2bf(v.y); o.z = f2bf(v.z); o.w = f2bf(v.w);
        *(ushort4*)(out + (size_t)i * 4) = o;
    }
}

// ---------- transpose + cast: W[K,N] fp32 -> WT[N,K] bf16 -------------------
__global__ __launch_bounds__(256) void transpose_cast_kernel(
    const float* __restrict__ W, unsigned short* __restrict__ WT, int K, int N)
{
    __shared__ float tile[32][33];
    const int k0 = blockIdx.y * 32;
    const int n0 = blockIdx.x * 32;
    const int tr = threadIdx.x >> 3;
    const int tc = (threadIdx.x & 7) * 4;

    float4 v = *(const float4*)(W + (size_t)(k0 + tr) * N + n0 + tc);
    tile[tr][tc + 0] = v.x;
    tile[tr][tc + 1] = v.y;
    tile[tr][tc + 2] = v.z;
    tile[tr][tc + 3] = v.w;
    __syncthreads();

    ushort4 o;
    o.x = f2bf(tile[tc + 0][tr]);
    o.y = f2bf(tile[tc + 1][tr]);
    o.z = f2bf(tile[tc + 2][tr]);
    o.w = f2bf(tile[tc + 3][tr]);
    *(ushort4*)(WT + (size_t)(n0 + tr) * K + k0 + tc) = o;
}

// ---------- row L2-normalize fp32 -> bf16, width 512 ------------------------
__global__ __launch_bounds__(128) void normalize_cast_kernel(
    const float* __restrict__ X, unsigned short* __restrict__ Y)
{
    const int r = blockIdx.x;
    const int t = threadIdx.x;
    const float* row = X + (size_t)r * 512;
    float4 v = *(const float4*)(row + t * 4);
    float ss = v.x * v.x + v.y * v.y + v.z * v.z + v.w * v.w;
#pragma unroll
    for (int off = 32; off > 0; off >>= 1) ss += __shfl_down(ss, off, 64);
    __shared__ float sred[2];
    if ((t & 63) == 0) sred[t >> 6] = ss;
    __syncthreads();
    float inv = 1.0f / sqrtf(sred[0] + sred[1]);
    ushort4 o;
    o.x = f2bf(v.x * inv); o.y = f2bf(v.y * inv);
    o.z = f2bf(v.z * inv); o.w = f2bf(v.w * inv);
    *(ushort4*)(Y + (size_t)r * 512 + t * 4) = o;
}

// ---------- per-row mining + loss -------------------------------------------
// 512 threads/block, one block per row. Linear 22-bit monotone key:
//   key = 2.1e6 + floor(s * 1e5), excluded (diag/noise) -> 0.
// 2-pass 11-bit radix select with parallel suffix scan; then weights+LSE.
__device__ __forceinline__ unsigned qkey(float s, bool excl)
{
    if (excl) return 0u;
    int k = 2100000 + (int)floorf(s * 100000.0f);
    k = k < 1 ? 1 : (k > 4194303 ? 4194303 : k);
    return (unsigned)k;
}

__global__ __launch_bounds__(512) void row_loss_kernel(
    const float* __restrict__ S, int row_base,
    const float* __restrict__ mw, int midx, float* __restrict__ accum)
{
    __shared__ float row[8192];
    __shared__ unsigned hist[2048];
    __shared__ unsigned part[512];
    __shared__ unsigned sh_b, sh_t;
    __shared__ float red[8];
    __shared__ float sh_diag, sh_bmax;

    const int t = threadIdx.x;
    const int i = row_base + blockIdx.x;          // diag column index
    const float* Srow = S + (size_t)blockIdx.x * 8192;

    for (int j = t * 4; j < 8192; j += 2048)
        *(float4*)(&row[j]) = *(const float4*)(&Srow[j]);
    __syncthreads();

    unsigned target = 4096;
    unsigned bucket = 0;
    unsigned lowb   = 0;

    for (int pass = 0; pass < 2; ++pass) {
        // zero hist
        for (int b = t; b < 2048; b += 512) hist[b] = 0;
        __syncthreads();

        for (int j = t; j < 8192; j += 512) {
            float s = row[j];
            unsigned key = qkey(s, (j == i) || (s > 9.0f));
            if (pass == 0)
                atomicAdd(&hist[key >> 11], 1u);
            else if ((key >> 11) == bucket)
                atomicAdd(&hist[key & 2047u], 1u);
        }
        __syncthreads();

        // per-thread partial (4 buckets each), then inclusive suffix scan
        unsigned local = hist[t * 4 + 0] + hist[t * 4 + 1]
                       + hist[t * 4 + 2] + hist[t * 4 + 3];
        part[t] = local;
        __syncthreads();
#pragma unroll
        for (int off = 1; off < 512; off <<= 1) {
            unsigned v = (t + off < 512) ? part[t + off] : 0u;
            __syncthreads();
            part[t] += v;
            __syncthreads();
        }
        unsigned above = (t < 511) ? part[t + 1] : 0u;
        if (part[t] >= target && above < target) {
            unsigned cum = above;
#pragma unroll
            for (int q = 3; q >= 0; --q) {
                unsigned c = hist[t * 4 + q];
                if (cum + c >= target) {
                    sh_b = (unsigned)(t * 4 + q);
                    sh_t = target - cum;
                    break;
                }
                cum += c;
            }
        }
        __syncthreads();
        if (pass == 0) { bucket = sh_b; target = sh_t; }
        else           { lowb = sh_b; }
        __syncthreads();
    }
    const unsigned tkey = (bucket << 11) | lowb;

    // --- apply weights, find max ---
    float lmax = -INFINITY;
    for (int j = t; j < 8192; j += 512) {
        float s = row[j];
        bool diag  = (j == i);
        bool noise = (!diag && s > 9.0f);
        unsigned key = qkey(s, diag || noise);
        float wgt = noise ? 0.5f : ((!diag && key >= tkey) ? 1.5f : 1.0f);
        float ws = s * wgt;
        row[j] = ws;
        if (diag) sh_diag = ws;
        lmax = fmaxf(lmax, ws);
    }
#pragma unroll
    for (int off = 32; off > 0; off >>= 1)
        lmax = fmaxf(lmax, __shfl_down(lmax, off, 64));
    if ((t & 63) == 0) red[t >> 6] = lmax;
    __syncthreads();
    if (t == 0) {
        float m = red[0];
#pragma unroll
        for (int q = 1; q < 8; ++q) m = fmaxf(m, red[q]);
        sh_bmax = m;
    }
    __syncthreads();
    const float bmax = sh_bmax;
    __syncthreads();

    float lsum = 0.0f;
    for (int j = t; j < 8192; j += 512)
        lsum += __expf(row[j] - bmax);
#pragma unroll
    for (int off = 32; off > 0; off >>= 1)
        lsum += __shfl_down(lsum, off, 64);
    if ((t & 63) == 0) red[t >> 6] = lsum;
    __syncthreads();
    if (t == 0) {
        float total = 0.0f;
#pragma unroll
        for (int q = 0; q < 8; ++q) total += red[q];
        float lse = bmax + logf(total);
        float ce = lse - sh_diag;
        atomicAdd(&accum[midx], ce * mw[(size_t)i * 2 + midx]);
    }
}

__global__ void zero_kernel(float* __restrict__ accum)
{
    if (threadIdx.x < 2) accum[threadIdx.x] = 0.0f;
}

__global__ void finalize_kernel(const float* __restrict__ accum,
                                float* __restrict__ out)
{
    out[0] = (accum[0] + accum[1]) * (1.0f / 16384.0f);
}

// ---------------------------------------------------------------------------
extern "C" void kernel_launch(void* const* d_in, const int* in_sizes, int n_in,
                              void* d_out, int out_size, void* d_ws, size_t ws_size,
                              hipStream_t stream)
{
    (void)in_sizes; (void)n_in; (void)out_size; (void)ws_size;

    const float* id_emb = (const float*)d_in[0];
    const float* feats[2] = { (const float*)d_in[1], (const float*)d_in[2] };
    const float* mw     = (const float*)d_in[3];
    const float* Wa[2]  = { (const float*)d_in[4],  (const float*)d_in[6]  };
    const float* ba[2]  = { (const float*)d_in[5],  (const float*)d_in[7]  };
    const float* W1[2]  = { (const float*)d_in[8],  (const float*)d_in[12] };
    const float* b1[2]  = { (const float*)d_in[9],  (const float*)d_in[13] };
    const float* W2[2]  = { (const float*)d_in[10], (const float*)d_in[14] };
    const float* b2[2]  = { (const float*)d_in[11], (const float*)d_in[15] };
    const int    Fdim[2] = { 768, 2048 };

    char* p = (char*)d_ws;
    unsigned short* idb   = (unsigned short*)p; p += (size_t)8192 * 1024 * 2;
    unsigned short* R1    = (unsigned short*)p; p += (size_t)8192 * 2048 * 2;
    unsigned short* WaT   = (unsigned short*)p; p += (size_t)1024 * 2048 * 2;
    unsigned short* W1T   = (unsigned short*)p; p += (size_t)1024 * 1024 * 2;
    unsigned short* W2T   = (unsigned short*)p; p += (size_t)512  * 1024 * 2;
    unsigned short* h1    = (unsigned short*)p; p += (size_t)8192 * 1024 * 2;
    unsigned short* mproj = (unsigned short*)p; p += (size_t)8192 * 512  * 2;
    unsigned short* iproj = (unsigned short*)p; p += (size_t)8192 * 512  * 2;
    float*          S     = (float*)p;          p += (size_t)CHUNK * 8192 * 4;
    float*          projf = (float*)S;
    float*          accum = (float*)p;

    zero_kernel<<<1, 64, 0, stream>>>(accum);

    cast_bf16_kernel<<<(8192 * 1024 / 4 + 255) / 256, 256, 0, stream>>>(
        id_emb, idb, 8192 * 1024 / 4);

    for (int m = 0; m < 2; ++m) {
        const int F = Fdim[m];
        unsigned short* featb = R1;
        unsigned short* h2    = R1;

        cast_bf16_kernel<<<(8192 * F / 4 + 255) / 256, 256, 0, stream>>>(
            feats[m], featb, 8192 * F / 4);
        transpose_cast_kernel<<<dim3(1024 / 32, F / 32), 256, 0, stream>>>(
            Wa[m], WaT, F, 1024);
        transpose_cast_kernel<<<dim3(1024 / 32, 1024 / 32), 256, 0, stream>>>(
            W1[m], W1T, 1024, 1024);
        transpose_cast_kernel<<<dim3(512 / 32, 1024 / 32), 256, 0, stream>>>(
            W2[m], W2T, 1024, 512);

        gemm_bt_mfma<<<dim3(1024 / 128, 8192 / 128), 256, 0, stream>>>(
            featb, F, WaT, F, h1, 1024, F, ba[m], 0, 1.0f, 1);
        gemm_bt_mfma<<<dim3(1024 / 128, 8192 / 128), 256, 0, stream>>>(
            h1, 1024, W1T, 1024, h2, 1024, 1024, b1[m], 1, 1.0f, 1);
        gemm_bt_mfma<<<dim3(512 / 128, 8192 / 128), 256, 0, stream>>>(
            h2, 1024, W2T, 1024, projf, 512, 1024, b2[m], 0, 1.0f, 0);
        normalize_cast_kernel<<<8192, 128, 0, stream>>>(projf, mproj);

        gemm_bt_mfma<<<dim3(1024 / 128, 8192 / 128), 256, 0, stream>>>(
            idb, 1024, W1T, 1024, h1, 1024, 1024, b1[m], 1, 1.0f, 1);
        gemm_bt_mfma<<<dim3(512 / 128, 8192 / 128), 256, 0, stream>>>(
            h1, 1024, W2T, 1024, projf, 512, 1024, b2[m], 0, 1.0f, 0);
        normalize_cast_kernel<<<8192, 128, 0, stream>>>(projf, iproj);

        for (int c = 0; c < B_ROWS / CHUNK; ++c) {
            gemm_bt_mfma<<<dim3(8192 / 128, CHUNK / 128), 256, 0, stream>>>(
                iproj + (size_t)c * CHUNK * 512, 512, mproj, 512,
                S, 8192, 512, nullptr, 0, 10.0f, 0);
            row_loss_kernel<<<CHUNK, 512, 0, stream>>>(
                S, c * CHUNK, mw, m, accum);
        }
    }

    finalize_kernel<<<1, 1, 0, stream>>>(accum, (float*)d_out);
}

// Round 4
// 1211.373 us; speedup vs baseline: 5.3367x; 1.2048x over previous
//
#include <hip/hip_runtime.h>
#include <math.h>
#include <stdint.h>

// ---------------------------------------------------------------------------
// IntraModalContrastive loss. Round 3:
//  - fused projector: X=[adapter(feat); id] (16384 rows) -> H -> P, halving
//    dispatches and doubling GEMM grids (4 blocks/CU).
//  - sim chunk 2048 rows (grid 1024), buffers aliased, ws unchanged ~119 MB.
//  - XCD-slice + GROUP_M swizzle on 1D-grid GEMM for L2 tile reuse.
// ---------------------------------------------------------------------------

typedef __attribute__((ext_vector_type(4))) float  floatx4;
typedef __attribute__((ext_vector_type(8))) __bf16 bf16x8;

__device__ __forceinline__ unsigned short f2bf(float f)
{
    unsigned u = __float_as_uint(f);
    unsigned r = (u + 0x7FFFu + ((u >> 16) & 1u)) >> 16;
    return (unsigned short)r;
}

__device__ __forceinline__ void gld_lds16(const void* g, void* l)
{
    __builtin_amdgcn_global_load_lds(
        (const __attribute__((address_space(1))) void*)g,
        (__attribute__((address_space(3))) void*)(uint32_t)(uintptr_t)l,
        16, 0, 0);
}

// ---------- bf16 MFMA GEMM, 1D grid + XCD/group swizzle ---------------------
// C[M,N] = ep(scale*(A @ B^T) + bias); A: MxK bf16 (lda), B: NxK bf16 (ldb).
// Tile 128x128, BK=32, 256 threads. grid.x == (M/128)*(N/128), divisible by 8.
__global__ __launch_bounds__(256) void gemm_bt_mfma(
    const unsigned short* __restrict__ A, int lda,
    const unsigned short* __restrict__ B, int ldb,
    void* __restrict__ C, int ldc, int M, int N, int K,
    const float* __restrict__ bias, int relu, float scale, int out_bf16)
{
    __shared__ __align__(16) unsigned short As[128 * 32];
    __shared__ __align__(16) unsigned short Bs[128 * 32];

    // --- block swizzle: contiguous slice per XCD, then GROUP_M=4 ---
    const int num_n = N >> 7;
    const int per   = gridDim.x >> 3;
    const int pid   = blockIdx.x;
    const int npid  = (pid & 7) * per + (pid >> 3);
    const int width = 4 * num_n;
    const int group = npid / width;
    const int rem   = npid - group * width;
    const int pm    = group * 4 + (rem & 3);       // num_m divisible by 4
    const int pn    = rem >> 2;

    const int t    = threadIdx.x;
    const int lane = t & 63;
    const int w    = t >> 6;
    const int wr   = w >> 1;
    const int wc   = w & 1;
    const size_t m0 = (size_t)pm * 128;
    const size_t n0 = (size_t)pn * 128;

    floatx4 acc[4][4] = {};

    const unsigned short* Abase = A + m0 * (size_t)lda;
    const unsigned short* Bbase = B + n0 * (size_t)ldb;

    const int s_row = t >> 2;
    const int s_kof = (t & 3) << 3;

    for (int k0 = 0; k0 < K; k0 += 32) {
#pragma unroll
        for (int it = 0; it < 2; ++it) {
            const int idx = it * 256 + t;
            const int row = it * 64 + s_row;
            gld_lds16(Abase + (size_t)row * lda + k0 + s_kof, As + idx * 8);
            gld_lds16(Bbase + (size_t)row * ldb + k0 + s_kof, Bs + idx * 8);
        }
        __syncthreads();

        bf16x8 af[4], bf[4];
#pragma unroll
        for (int i = 0; i < 4; ++i) {
            af[i] = *(const bf16x8*)(As + ((wr * 64 + i * 16 + (lane & 15)) * 32 + (lane >> 4) * 8));
            bf[i] = *(const bf16x8*)(Bs + ((wc * 64 + i * 16 + (lane & 15)) * 32 + (lane >> 4) * 8));
        }
#pragma unroll
        for (int i = 0; i < 4; ++i)
#pragma unroll
            for (int j = 0; j < 4; ++j)
                acc[i][j] = __builtin_amdgcn_mfma_f32_16x16x32_bf16(
                    af[i], bf[j], acc[i][j], 0, 0, 0);
        __syncthreads();
    }

    const int col   = lane & 15;
    const int rquad = (lane >> 4) * 4;
#pragma unroll
    for (int j = 0; j < 4; ++j) {
        const size_t gc = n0 + wc * 64 + j * 16 + col;
        const float bv = bias ? bias[gc] : 0.0f;
#pragma unroll
        for (int i = 0; i < 4; ++i) {
            const size_t gr0 = m0 + wr * 64 + i * 16 + rquad;
#pragma unroll
            for (int r = 0; r < 4; ++r) {
                float v = acc[i][j][r] * scale + bv;
                if (relu) v = fmaxf(v, 0.0f);
                if (out_bf16)
                    ((unsigned short*)C)[(gr0 + r) * (size_t)ldc + gc] = f2bf(v);
                else
                    ((float*)C)[(gr0 + r) * (size_t)ldc + gc] = v;
            }
        }
    }
}

// ---------- elementwise fp32 -> bf16 cast -----------------------------------
__global__ __launch_bounds__(256) void cast_bf16_kernel(
    const float* __restrict__ in, unsigned short* __restrict__ out, int n4)
{
    const int i = blockIdx.x * 256 + threadIdx.x;
    if (i < n4) {
        float4 v = *(const float4*)(in + (size_t)i * 4);
        ushort4 o;
        o.x = f2bf(v.x); o.y = f2bf(v.y); o.z = f2bf(v.z); o.w = f2bf(v.w);
        *(ushort4*)(out + (size_t)i * 4) = o;
    }
}

// ---------- transpose + cast: W[K,N] fp32 -> WT[N,K] bf16 -------------------
__global__ __launch_bounds__(256) void transpose_cast_kernel(
    const float* __restrict__ W, unsigned short* __restrict__ WT, int K, int N)
{
    __shared__ float tile[32][33];
    const int k0 = blockIdx.y * 32;
    const int n0 = blockIdx.x * 32;
    const int tr = threadIdx.x >> 3;
    const int tc = (threadIdx.x & 7) * 4;

    float4 v = *(const float4*)(W + (size_t)(k0 + tr) * N + n0 + tc);
    tile[tr][tc + 0] = v.x;
    tile[tr][tc + 1] = v.y;
    tile[tr][tc + 2] = v.z;
    tile[tr][tc + 3] = v.w;
    __syncthreads();

    ushort4 o;
    o.x = f2bf(tile[tc + 0][tr]);
    o.y = f2bf(tile[tc + 1][tr]);
    o.z = f2bf(tile[tc + 2][tr]);
    o.w = f2bf(tile[tc + 3][tr]);
    *(ushort4*)(WT + (size_t)(n0 + tr) * K + k0 + tc) = o;
}

// ---------- row L2-normalize fp32 -> bf16, width 512 ------------------------
__global__ __launch_bounds__(128) void normalize_cast_kernel(
    const float* __restrict__ X, unsigned short* __restrict__ Y)
{
    const int r = blockIdx.x;
    const int t = threadIdx.x;
    const float* row = X + (size_t)r * 512;
    float4 v = *(const float4*)(row + t * 4);
    float ss = v.x * v.x + v.y * v.y + v.z * v.z + v.w * v.w;
#pragma unroll
    for (int off = 32; off > 0; off >>= 1) ss += __shfl_down(ss, off, 64);
    __shared__ float sred[2];
    if ((t & 63) == 0) sred[t >> 6] = ss;
    __syncthreads();
    float inv = 1.0f / sqrtf(sred[0] + sred[1]);
    ushort4 o;
    o.x = f2bf(v.x * inv); o.y = f2bf(v.y * inv);
    o.z = f2bf(v.z * inv); o.w = f2bf(v.w * inv);
    *(ushort4*)(Y + (size_t)r * 512 + t * 4) = o;
}

// ---------- per-row mining + loss -------------------------------------------
__device__ __forceinline__ unsigned qkey(float s, bool excl)
{
    if (excl) return 0u;
    int k = 2100000 + (int)floorf(s * 100000.0f);
    k = k < 1 ? 1 : (k > 4194303 ? 4194303 : k);
    return (unsigned)k;
}

__global__ __launch_bounds__(512) void row_loss_kernel(
    const float* __restrict__ S, int row_base,
    const float* __restrict__ mw, int midx, float* __restrict__ accum)
{
    __shared__ float row[8192];
    __shared__ unsigned hist[2048];
    __shared__ unsigned part[512];
    __shared__ unsigned sh_b, sh_t;
    __shared__ float red[8];
    __shared__ float sh_diag, sh_bmax;

    const int t = threadIdx.x;
    const int i = row_base + blockIdx.x;
    const float* Srow = S + (size_t)blockIdx.x * 8192;

    for (int j = t * 4; j < 8192; j += 2048)
        *(float4*)(&row[j]) = *(const float4*)(&Srow[j]);
    __syncthreads();

    unsigned target = 4096;
    unsigned bucket = 0;
    unsigned lowb   = 0;

    for (int pass = 0; pass < 2; ++pass) {
        for (int b = t; b < 2048; b += 512) hist[b] = 0;
        __syncthreads();

        for (int j = t; j < 8192; j += 512) {
            float s = row[j];
            unsigned key = qkey(s, (j == i) || (s > 9.0f));
            if (pass == 0)
                atomicAdd(&hist[key >> 11], 1u);
            else if ((key >> 11) == bucket)
                atomicAdd(&hist[key & 2047u], 1u);
        }
        __syncthreads();

        unsigned local = hist[t * 4 + 0] + hist[t * 4 + 1]
                       + hist[t * 4 + 2] + hist[t * 4 + 3];
        part[t] = local;
        __syncthreads();
#pragma unroll
        for (int off = 1; off < 512; off <<= 1) {
            unsigned v = (t + off < 512) ? part[t + off] : 0u;
            __syncthreads();
            part[t] += v;
            __syncthreads();
        }
        unsigned above = (t < 511) ? part[t + 1] : 0u;
        if (part[t] >= target && above < target) {
            unsigned cum = above;
#pragma unroll
            for (int q = 3; q >= 0; --q) {
                unsigned c = hist[t * 4 + q];
                if (cum + c >= target) {
                    sh_b = (unsigned)(t * 4 + q);
                    sh_t = target - cum;
                    break;
                }
                cum += c;
            }
        }
        __syncthreads();
        if (pass == 0) { bucket = sh_b; target = sh_t; }
        else           { lowb = sh_b; }
        __syncthreads();
    }
    const unsigned tkey = (bucket << 11) | lowb;

    float lmax = -INFINITY;
    for (int j = t; j < 8192; j += 512) {
        float s = row[j];
        bool diag  = (j == i);
        bool noise = (!diag && s > 9.0f);
        unsigned key = qkey(s, diag || noise);
        float wgt = noise ? 0.5f : ((!diag && key >= tkey) ? 1.5f : 1.0f);
        float ws = s * wgt;
        row[j] = ws;
        if (diag) sh_diag = ws;
        lmax = fmaxf(lmax, ws);
    }
#pragma unroll
    for (int off = 32; off > 0; off >>= 1)
        lmax = fmaxf(lmax, __shfl_down(lmax, off, 64));
    if ((t & 63) == 0) red[t >> 6] = lmax;
    __syncthreads();
    if (t == 0) {
        float m = red[0];
#pragma unroll
        for (int q = 1; q < 8; ++q) m = fmaxf(m, red[q]);
        sh_bmax = m;
    }
    __syncthreads();
    const float bmax = sh_bmax;
    __syncthreads();

    float lsum = 0.0f;
    for (int j = t; j < 8192; j += 512)
        lsum += __expf(row[j] - bmax);
#pragma unroll
    for (int off = 32; off > 0; off >>= 1)
        lsum += __shfl_down(lsum, off, 64);
    if ((t & 63) == 0) red[t >> 6] = lsum;
    __syncthreads();
    if (t == 0) {
        float total = 0.0f;
#pragma unroll
        for (int q = 0; q < 8; ++q) total += red[q];
        float lse = bmax + logf(total);
        float ce = lse - sh_diag;
        atomicAdd(&accum[midx], ce * mw[(size_t)i * 2 + midx]);
    }
}

__global__ void zero_kernel(float* __restrict__ accum)
{
    if (threadIdx.x < 2) accum[threadIdx.x] = 0.0f;
}

__global__ void finalize_kernel(const float* __restrict__ accum,
                                float* __restrict__ out)
{
    out[0] = (accum[0] + accum[1]) * (1.0f / 16384.0f);
}

// ---------------------------------------------------------------------------
extern "C" void kernel_launch(void* const* d_in, const int* in_sizes, int n_in,
                              void* d_out, int out_size, void* d_ws, size_t ws_size,
                              hipStream_t stream)
{
    (void)in_sizes; (void)n_in; (void)out_size; (void)ws_size;

    const float* id_emb = (const float*)d_in[0];
    const float* feats[2] = { (const float*)d_in[1], (const float*)d_in[2] };
    const float* mw     = (const float*)d_in[3];
    const float* Wa[2]  = { (const float*)d_in[4],  (const float*)d_in[6]  };
    const float* ba[2]  = { (const float*)d_in[5],  (const float*)d_in[7]  };
    const float* W1[2]  = { (const float*)d_in[8],  (const float*)d_in[12] };
    const float* b1[2]  = { (const float*)d_in[9],  (const float*)d_in[13] };
    const float* W2[2]  = { (const float*)d_in[10], (const float*)d_in[14] };
    const float* b2[2]  = { (const float*)d_in[11], (const float*)d_in[15] };
    const int    Fdim[2] = { 768, 2048 };

    // Buffer pool (~119 MB), aliased across phases:
    //   WaT(4) W1T(2) W2T(1) | featb(32, P-fp32 aliases) | X(32) H(32) [S(64)
    //   aliases X+H] | PB(16) | accum
    char* p = (char*)d_ws;
    unsigned short* WaT   = (unsigned short*)p; p += (size_t)1024 * 2048 * 2;  //  4 MB
    unsigned short* W1T   = (unsigned short*)p; p += (size_t)1024 * 1024 * 2;  //  2 MB
    unsigned short* W2T   = (unsigned short*)p; p += (size_t)512  * 1024 * 2;  //  1 MB
    unsigned short* featb = (unsigned short*)p; p += (size_t)8192 * 2048 * 2;  // 32 MB
    unsigned short* X     = (unsigned short*)p; p += (size_t)16384 * 1024 * 2; // 32 MB
    unsigned short* H     = (unsigned short*)p; p += (size_t)16384 * 1024 * 2; // 32 MB
    unsigned short* PB    = (unsigned short*)p; p += (size_t)16384 * 512  * 2; // 16 MB
    float*          accum = (float*)p;
    float*          Pf    = (float*)featb;     // 16384x512 fp32 = 32 MB
    float*          S     = (float*)X;         // 2048x8192 fp32 = 64 MB

    zero_kernel<<<1, 64, 0, stream>>>(accum);

    for (int m = 0; m < 2; ++m) {
        const int F = Fdim[m];

        cast_bf16_kernel<<<(8192 * F / 4 + 255) / 256, 256, 0, stream>>>(
            feats[m], featb, 8192 * F / 4);
        transpose_cast_kernel<<<dim3(1024 / 32, F / 32), 256, 0, stream>>>(
            Wa[m], WaT, F, 1024);
        transpose_cast_kernel<<<dim3(1024 / 32, 1024 / 32), 256, 0, stream>>>(
            W1[m], W1T, 1024, 1024);
        transpose_cast_kernel<<<dim3(512 / 32, 1024 / 32), 256, 0, stream>>>(
            W2[m], W2T, 1024, 512);

        // X[0:8192]  = feat @ Wa + ba  (bf16)
        gemm_bt_mfma<<<(8192 / 128) * (1024 / 128), 256, 0, stream>>>(
            featb, F, WaT, F, X, 1024, 8192, 1024, F, ba[m], 0, 1.0f, 1);
        // X[8192:]   = id (bf16 cast)
        cast_bf16_kernel<<<(8192 * 1024 / 4 + 255) / 256, 256, 0, stream>>>(
            id_emb, X + (size_t)8192 * 1024, 8192 * 1024 / 4);

        // H = relu(X @ W1 + b1)        (16384 x 1024, bf16)
        gemm_bt_mfma<<<(16384 / 128) * (1024 / 128), 256, 0, stream>>>(
            X, 1024, W1T, 1024, H, 1024, 16384, 1024, 1024, b1[m], 1, 1.0f, 1);
        // Pf = H @ W2 + b2             (16384 x 512, fp32; overlays featb)
        gemm_bt_mfma<<<(16384 / 128) * (512 / 128), 256, 0, stream>>>(
            H, 1024, W2T, 1024, Pf, 512, 16384, 512, 1024, b2[m], 0, 1.0f, 0);
        // PB = normalize(Pf)           (modal rows 0:8192, id rows 8192:)
        normalize_cast_kernel<<<16384, 128, 0, stream>>>(Pf, PB);

        const unsigned short* mproj = PB;
        const unsigned short* iproj = PB + (size_t)8192 * 512;

        for (int c = 0; c < 4; ++c) {
            // S = 10 * id_proj[chunk 2048] @ modal_proj^T  (2048 x 8192 fp32)
            gemm_bt_mfma<<<(2048 / 128) * (8192 / 128), 256, 0, stream>>>(
                iproj + (size_t)c * 2048 * 512, 512, mproj, 512,
                S, 8192, 2048, 8192, 512, nullptr, 0, 10.0f, 0);
            row_loss_kernel<<<2048, 512, 0, stream>>>(
                S, c * 2048, mw, m, accum);
        }
    }

    finalize_kernel<<<1, 1, 0, stream>>>(accum, (float*)d_out);
}

// Round 5
// 993.730 us; speedup vs baseline: 6.5055x; 1.2190x over previous
//
#include <hip/hip_runtime.h>
#include <math.h>
#include <stdint.h>

// ---------------------------------------------------------------------------
// IntraModalContrastive loss. Round 4:
//  - S stored bf16 (half traffic), chunk 4096 rows (2 sim GEMM + 2 loss
//    dispatches per modality).
//  - row_loss v2: single 12-bit radix pass (4096 buckets), shuffle-based
//    suffix scan (~4 barriers), 3 element sweeps, 32 KB LDS -> 4 blocks/CU.
// ---------------------------------------------------------------------------

typedef __attribute__((ext_vector_type(4))) float  floatx4;
typedef __attribute__((ext_vector_type(8))) __bf16 bf16x8;

__device__ __forceinline__ unsigned short f2bf(float f)
{
    unsigned u = __float_as_uint(f);
    unsigned r = (u + 0x7FFFu + ((u >> 16) & 1u)) >> 16;
    return (unsigned short)r;
}

__device__ __forceinline__ float bf2f(unsigned short u)
{
    return __uint_as_float((unsigned)u << 16);
}

__device__ __forceinline__ void gld_lds16(const void* g, void* l)
{
    __builtin_amdgcn_global_load_lds(
        (const __attribute__((address_space(1))) void*)g,
        (__attribute__((address_space(3))) void*)(uint32_t)(uintptr_t)l,
        16, 0, 0);
}

// ---------- bf16 MFMA GEMM, 1D grid + XCD/group swizzle ---------------------
// C[M,N] = ep(scale*(A @ B^T) + bias); A: MxK bf16 (lda), B: NxK bf16 (ldb).
// Tile 128x128, BK=32, 256 threads. grid.x == (M/128)*(N/128), divisible by 8.
__global__ __launch_bounds__(256) void gemm_bt_mfma(
    const unsigned short* __restrict__ A, int lda,
    const unsigned short* __restrict__ B, int ldb,
    void* __restrict__ C, int ldc, int M, int N, int K,
    const float* __restrict__ bias, int relu, float scale, int out_bf16)
{
    __shared__ __align__(16) unsigned short As[128 * 32];
    __shared__ __align__(16) unsigned short Bs[128 * 32];

    const int num_n = N >> 7;
    const int per   = gridDim.x >> 3;
    const int pid   = blockIdx.x;
    const int npid  = (pid & 7) * per + (pid >> 3);
    const int width = 4 * num_n;
    const int group = npid / width;
    const int rem   = npid - group * width;
    const int pm    = group * 4 + (rem & 3);
    const int pn    = rem >> 2;

    const int t    = threadIdx.x;
    const int lane = t & 63;
    const int w    = t >> 6;
    const int wr   = w >> 1;
    const int wc   = w & 1;
    const size_t m0 = (size_t)pm * 128;
    const size_t n0 = (size_t)pn * 128;

    floatx4 acc[4][4] = {};

    const unsigned short* Abase = A + m0 * (size_t)lda;
    const unsigned short* Bbase = B + n0 * (size_t)ldb;

    const int s_row = t >> 2;
    const int s_kof = (t & 3) << 3;

    for (int k0 = 0; k0 < K; k0 += 32) {
#pragma unroll
        for (int it = 0; it < 2; ++it) {
            const int idx = it * 256 + t;
            const int row = it * 64 + s_row;
            gld_lds16(Abase + (size_t)row * lda + k0 + s_kof, As + idx * 8);
            gld_lds16(Bbase + (size_t)row * ldb + k0 + s_kof, Bs + idx * 8);
        }
        __syncthreads();

        bf16x8 af[4], bf[4];
#pragma unroll
        for (int i = 0; i < 4; ++i) {
            af[i] = *(const bf16x8*)(As + ((wr * 64 + i * 16 + (lane & 15)) * 32 + (lane >> 4) * 8));
            bf[i] = *(const bf16x8*)(Bs + ((wc * 64 + i * 16 + (lane & 15)) * 32 + (lane >> 4) * 8));
        }
#pragma unroll
        for (int i = 0; i < 4; ++i)
#pragma unroll
            for (int j = 0; j < 4; ++j)
                acc[i][j] = __builtin_amdgcn_mfma_f32_16x16x32_bf16(
                    af[i], bf[j], acc[i][j], 0, 0, 0);
        __syncthreads();
    }

    const int col   = lane & 15;
    const int rquad = (lane >> 4) * 4;
#pragma unroll
    for (int j = 0; j < 4; ++j) {
        const size_t gc = n0 + wc * 64 + j * 16 + col;
        const float bv = bias ? bias[gc] : 0.0f;
#pragma unroll
        for (int i = 0; i < 4; ++i) {
            const size_t gr0 = m0 + wr * 64 + i * 16 + rquad;
#pragma unroll
            for (int r = 0; r < 4; ++r) {
                float v = acc[i][j][r] * scale + bv;
                if (relu) v = fmaxf(v, 0.0f);
                if (out_bf16)
                    ((unsigned short*)C)[(gr0 + r) * (size_t)ldc + gc] = f2bf(v);
                else
                    ((float*)C)[(gr0 + r) * (size_t)ldc + gc] = v;
            }
        }
    }
}

// ---------- elementwise fp32 -> bf16 cast -----------------------------------
__global__ __launch_bounds__(256) void cast_bf16_kernel(
    const float* __restrict__ in, unsigned short* __restrict__ out, int n4)
{
    const int i = blockIdx.x * 256 + threadIdx.x;
    if (i < n4) {
        float4 v = *(const float4*)(in + (size_t)i * 4);
        ushort4 o;
        o.x = f2bf(v.x); o.y = f2bf(v.y); o.z = f2bf(v.z); o.w = f2bf(v.w);
        *(ushort4*)(out + (size_t)i * 4) = o;
    }
}

// ---------- transpose + cast: W[K,N] fp32 -> WT[N,K] bf16 -------------------
__global__ __launch_bounds__(256) void transpose_cast_kernel(
    const float* __restrict__ W, unsigned short* __restrict__ WT, int K, int N)
{
    __shared__ float tile[32][33];
    const int k0 = blockIdx.y * 32;
    const int n0 = blockIdx.x * 32;
    const int tr = threadIdx.x >> 3;
    const int tc = (threadIdx.x & 7) * 4;

    float4 v = *(const float4*)(W + (size_t)(k0 + tr) * N + n0 + tc);
    tile[tr][tc + 0] = v.x;
    tile[tr][tc + 1] = v.y;
    tile[tr][tc + 2] = v.z;
    tile[tr][tc + 3] = v.w;
    __syncthreads();

    ushort4 o;
    o.x = f2bf(tile[tc + 0][tr]);
    o.y = f2bf(tile[tc + 1][tr]);
    o.z = f2bf(tile[tc + 2][tr]);
    o.w = f2bf(tile[tc + 3][tr]);
    *(ushort4*)(WT + (size_t)(n0 + tr) * K + k0 + tc) = o;
}

// ---------- row L2-normalize fp32 -> bf16, width 512 ------------------------
__global__ __launch_bounds__(128) void normalize_cast_kernel(
    const float* __restrict__ X, unsigned short* __restrict__ Y)
{
    const int r = blockIdx.x;
    const int t = threadIdx.x;
    const float* row = X + (size_t)r * 512;
    float4 v = *(const float4*)(row + t * 4);
    float ss = v.x * v.x + v.y * v.y + v.z * v.z + v.w * v.w;
#pragma unroll
    for (int off = 32; off > 0; off >>= 1) ss += __shfl_down(ss, off, 64);
    __shared__ float sred[2];
    if ((t & 63) == 0) sred[t >> 6] = ss;
    __syncthreads();
    float inv = 1.0f / sqrtf(sred[0] + sred[1]);
    ushort4 o;
    o.x = f2bf(v.x * inv); o.y = f2bf(v.y * inv);
    o.z = f2bf(v.z * inv); o.w = f2bf(v.w * inv);
    *(ushort4*)(Y + (size_t)r * 512 + t * 4) = o;
}

// ---------- per-row mining + loss (v2) --------------------------------------
// 512 threads/block, one block per row. S row in bf16. Single 12-bit radix
// pass (4096 buckets, resolution 0.005), shuffle suffix scan, 3 sweeps.
__global__ __launch_bounds__(512) void row_loss_kernel(
    const unsigned short* __restrict__ S, int row_base,
    const float* __restrict__ mw, int midx, float* __restrict__ accum)
{
    __shared__ unsigned short rowu[8192];   // 16 KB
    __shared__ unsigned hist[4096];         // 16 KB
    __shared__ unsigned wtot[8];
    __shared__ float fred[8];
    __shared__ unsigned sh_b;
    __shared__ float sh_diag, sh_bmax;

    const int t    = threadIdx.x;
    const int lane = t & 63;
    const int wv   = t >> 6;
    const int i    = row_base + blockIdx.x;     // diag column index
    const unsigned short* Srow = S + (size_t)blockIdx.x * 8192;

    for (int j = t * 8; j < 8192; j += 4096)
        *(uint4*)(&rowu[j]) = *(const uint4*)(&Srow[j]);
    for (int b = t; b < 4096; b += 512) hist[b] = 0;
    __syncthreads();

    // pass A: histogram of included entries
    for (int j = t; j < 8192; j += 512) {
        float s = bf2f(rowu[j]);
        bool excl = (j == i) || (s > 9.0f);
        if (!excl) {
            int k = (int)((s + 10.25f) * 200.0f);
            k = k < 1 ? 1 : (k > 4095 ? 4095 : k);
            atomicAdd(&hist[k], 1u);
        }
    }
    __syncthreads();

    // suffix scan: thread owns buckets [t*8, t*8+8)
    unsigned local = 0;
#pragma unroll
    for (int q = 0; q < 8; ++q) local += hist[t * 8 + q];
    unsigned suf = local;
#pragma unroll
    for (int off = 1; off < 64; off <<= 1) {
        unsigned v = __shfl_down(suf, off, 64);
        if (lane + off < 64) suf += v;
    }
    if (lane == 0) wtot[wv] = suf;
    __syncthreads();
    unsigned wsuf = 0;
#pragma unroll
    for (int q = 0; q < 8; ++q) wsuf += (q > wv) ? wtot[q] : 0u;
    suf += wsuf;                              // inclusive suffix from bucket t*8

    const unsigned target = 4096;
    const unsigned above  = suf - local;      // suffix from (t+1)*8
    if (suf >= target && above < target) {
        unsigned cum = above;
        int bsel = t * 8;
#pragma unroll
        for (int q = 7; q >= 0; --q) {
            unsigned c = hist[t * 8 + q];
            if (cum + c >= target) { bsel = t * 8 + q; break; }
            cum += c;
        }
        sh_b = (unsigned)bsel;
    }
    if (t == 0 && suf < target) sh_b = 1u;    // fewer than K finite: all hard
    __syncthreads();
    const unsigned bsel = sh_b;

    // pass B: weights + max (+ diag)
    float lmax = -INFINITY;
    for (int j = t; j < 8192; j += 512) {
        float s = bf2f(rowu[j]);
        bool diag  = (j == i);
        bool noise = (!diag && s > 9.0f);
        int k = (int)((s + 10.25f) * 200.0f);
        k = k < 1 ? 1 : (k > 4095 ? 4095 : k);
        bool hard = !diag && !noise && ((unsigned)k >= bsel);
        float wgt = noise ? 0.5f : (hard ? 1.5f : 1.0f);
        float ws = s * wgt;
        if (diag) sh_diag = ws;
        lmax = fmaxf(lmax, ws);
    }
#pragma unroll
    for (int off = 32; off > 0; off >>= 1)
        lmax = fmaxf(lmax, __shfl_down(lmax, off, 64));
    if (lane == 0) fred[wv] = lmax;
    __syncthreads();
    if (t == 0) {
        float m = fred[0];
#pragma unroll
        for (int q = 1; q < 8; ++q) m = fmaxf(m, fred[q]);
        sh_bmax = m;
    }
    __syncthreads();
    const float bmax = sh_bmax;

    // pass C: exp-sum (recompute weights)
    float lsum = 0.0f;
    for (int j = t; j < 8192; j += 512) {
        float s = bf2f(rowu[j]);
        bool diag  = (j == i);
        bool noise = (!diag && s > 9.0f);
        int k = (int)((s + 10.25f) * 200.0f);
        k = k < 1 ? 1 : (k > 4095 ? 4095 : k);
        bool hard = !diag && !noise && ((unsigned)k >= bsel);
        float wgt = noise ? 0.5f : (hard ? 1.5f : 1.0f);
        lsum += __expf(s * wgt - bmax);
    }
#pragma unroll
    for (int off = 32; off > 0; off >>= 1)
        lsum += __shfl_down(lsum, off, 64);
    if (lane == 0) fred[wv] = lsum;
    __syncthreads();
    if (t == 0) {
        float total = 0.0f;
#pragma unroll
        for (int q = 0; q < 8; ++q) total += fred[q];
        float lse = bmax + logf(total);
        float ce = lse - sh_diag;
        atomicAdd(&accum[midx], ce * mw[(size_t)i * 2 + midx]);
    }
}

__global__ void zero_kernel(float* __restrict__ accum)
{
    if (threadIdx.x < 2) accum[threadIdx.x] = 0.0f;
}

__global__ void finalize_kernel(const float* __restrict__ accum,
                                float* __restrict__ out)
{
    out[0] = (accum[0] + accum[1]) * (1.0f / 16384.0f);
}

// ---------------------------------------------------------------------------
extern "C" void kernel_launch(void* const* d_in, const int* in_sizes, int n_in,
                              void* d_out, int out_size, void* d_ws, size_t ws_size,
                              hipStream_t stream)
{
    (void)in_sizes; (void)n_in; (void)out_size; (void)ws_size;

    const float* id_emb = (const float*)d_in[0];
    const float* feats[2] = { (const float*)d_in[1], (const float*)d_in[2] };
    const float* mw     = (const float*)d_in[3];
    const float* Wa[2]  = { (const float*)d_in[4],  (const float*)d_in[6]  };
    const float* ba[2]  = { (const float*)d_in[5],  (const float*)d_in[7]  };
    const float* W1[2]  = { (const float*)d_in[8],  (const float*)d_in[12] };
    const float* b1[2]  = { (const float*)d_in[9],  (const float*)d_in[13] };
    const float* W2[2]  = { (const float*)d_in[10], (const float*)d_in[14] };
    const float* b2[2]  = { (const float*)d_in[11], (const float*)d_in[15] };
    const int    Fdim[2] = { 768, 2048 };

    char* p = (char*)d_ws;
    unsigned short* WaT   = (unsigned short*)p; p += (size_t)1024 * 2048 * 2;  //  4 MB
    unsigned short* W1T   = (unsigned short*)p; p += (size_t)1024 * 1024 * 2;  //  2 MB
    unsigned short* W2T   = (unsigned short*)p; p += (size_t)512  * 1024 * 2;  //  1 MB
    unsigned short* featb = (unsigned short*)p; p += (size_t)8192 * 2048 * 2;  // 32 MB
    unsigned short* X     = (unsigned short*)p; p += (size_t)16384 * 1024 * 2; // 32 MB
    unsigned short* H     = (unsigned short*)p; p += (size_t)16384 * 1024 * 2; // 32 MB
    unsigned short* PB    = (unsigned short*)p; p += (size_t)16384 * 512  * 2; // 16 MB
    float*          accum = (float*)p;
    float*          Pf    = (float*)featb;       // 16384x512 fp32 = 32 MB
    unsigned short* S     = X;                   // 4096x8192 bf16 = 64 MB (X+H)

    zero_kernel<<<1, 64, 0, stream>>>(accum);

    for (int m = 0; m < 2; ++m) {
        const int F = Fdim[m];

        cast_bf16_kernel<<<(8192 * F / 4 + 255) / 256, 256, 0, stream>>>(
            feats[m], featb, 8192 * F / 4);
        transpose_cast_kernel<<<dim3(1024 / 32, F / 32), 256, 0, stream>>>(
            Wa[m], WaT, F, 1024);
        transpose_cast_kernel<<<dim3(1024 / 32, 1024 / 32), 256, 0, stream>>>(
            W1[m], W1T, 1024, 1024);
        transpose_cast_kernel<<<dim3(512 / 32, 1024 / 32), 256, 0, stream>>>(
            W2[m], W2T, 1024, 512);

        // X[0:8192]  = feat @ Wa + ba  (bf16)
        gemm_bt_mfma<<<(8192 / 128) * (1024 / 128), 256, 0, stream>>>(
            featb, F, WaT, F, X, 1024, 8192, 1024, F, ba[m], 0, 1.0f, 1);
        // X[8192:]   = id (bf16 cast)
        cast_bf16_kernel<<<(8192 * 1024 / 4 + 255) / 256, 256, 0, stream>>>(
            id_emb, X + (size_t)8192 * 1024, 8192 * 1024 / 4);

        // H = relu(X @ W1 + b1)        (16384 x 1024, bf16)
        gemm_bt_mfma<<<(16384 / 128) * (1024 / 128), 256, 0, stream>>>(
            X, 1024, W1T, 1024, H, 1024, 16384, 1024, 1024, b1[m], 1, 1.0f, 1);
        // Pf = H @ W2 + b2             (16384 x 512, fp32; overlays featb)
        gemm_bt_mfma<<<(16384 / 128) * (512 / 128), 256, 0, stream>>>(
            H, 1024, W2T, 1024, Pf, 512, 16384, 512, 1024, b2[m], 0, 1.0f, 0);
        // PB = normalize(Pf)           (modal rows 0:8192, id rows 8192:)
        normalize_cast_kernel<<<16384, 128, 0, stream>>>(Pf, PB);

        const unsigned short* mproj = PB;
        const unsigned short* iproj = PB + (size_t)8192 * 512;

        for (int c = 0; c < 2; ++c) {
            // S = 10 * id_proj[chunk 4096] @ modal_proj^T  (4096 x 8192 bf16)
            gemm_bt_mfma<<<(4096 / 128) * (8192 / 128), 256, 0, stream>>>(
                iproj + (size_t)c * 4096 * 512, 512, mproj, 512,
                S, 8192, 4096, 8192, 512, nullptr, 0, 10.0f, 1);
            row_loss_kernel<<<4096, 512, 0, stream>>>(
                S, c * 4096, mw, m, accum);
        }
    }

    finalize_kernel<<<1, 1, 0, stream>>>(accum, (float*)d_out);
}

// Round 6
// 924.921 us; speedup vs baseline: 6.9894x; 1.0744x over previous
//
#include <hip/hip_runtime.h>
#include <math.h>
#include <stdint.h>

// ---------------------------------------------------------------------------
// IntraModalContrastive loss. Round 5:
//  - GEMM epilogue: LDS-repack tile (bf16), coalesced uint4 global stores.
//    All GEMM outputs bf16 (P included); normalize is bf16 in-place.
//  - row_loss v3: no LDS row staging (re-read S from L2/L3), fixed bmax=16
//    (|w*s| <= 15.2), 2 vectorized sweeps, LDS = 16 KB hist only.
// ---------------------------------------------------------------------------

typedef __attribute__((ext_vector_type(4))) float  floatx4;
typedef __attribute__((ext_vector_type(8))) __bf16 bf16x8;

__device__ __forceinline__ unsigned short f2bf(float f)
{
    unsigned u = __float_as_uint(f);
    unsigned r = (u + 0x7FFFu + ((u >> 16) & 1u)) >> 16;
    return (unsigned short)r;
}

__device__ __forceinline__ float bf2f(unsigned short u)
{
    return __uint_as_float((unsigned)u << 16);
}

__device__ __forceinline__ void gld_lds16(const void* g, void* l)
{
    __builtin_amdgcn_global_load_lds(
        (const __attribute__((address_space(1))) void*)g,
        (__attribute__((address_space(3))) void*)(uint32_t)(uintptr_t)l,
        16, 0, 0);
}

#define EPW 136   // epilogue LDS row stride in shorts (272 B, 16B-aligned)

// ---------- bf16 MFMA GEMM, 1D grid + XCD/group swizzle, bf16 out -----------
// C[M,N] = ep(scale*(A @ B^T) + bias); A: MxK bf16 (lda), B: NxK bf16 (ldb).
// Tile 128x128, BK=32, 256 threads. grid.x == (M/128)*(N/128), divisible by 8.
__global__ __launch_bounds__(256) void gemm_bt_mfma(
    const unsigned short* __restrict__ A, int lda,
    const unsigned short* __restrict__ B, int ldb,
    unsigned short* __restrict__ C, int ldc, int M, int N, int K,
    const float* __restrict__ bias, int relu, float scale)
{
    // 34816 B: K-loop uses [0:16384) as As/Bs; epilogue uses all as 128xEPW.
    __shared__ __align__(16) unsigned short smem[128 * EPW];
    unsigned short* As = smem;
    unsigned short* Bs = smem + 4096;

    const int num_n = N >> 7;
    const int per   = gridDim.x >> 3;
    const int pid   = blockIdx.x;
    const int npid  = (pid & 7) * per + (pid >> 3);
    const int width = 4 * num_n;
    const int group = npid / width;
    const int rem   = npid - group * width;
    const int pm    = group * 4 + (rem & 3);
    const int pn    = rem >> 2;

    const int t    = threadIdx.x;
    const int lane = t & 63;
    const int w    = t >> 6;
    const int wr   = w >> 1;
    const int wc   = w & 1;
    const size_t m0 = (size_t)pm * 128;
    const size_t n0 = (size_t)pn * 128;

    floatx4 acc[4][4] = {};

    const unsigned short* Abase = A + m0 * (size_t)lda;
    const unsigned short* Bbase = B + n0 * (size_t)ldb;

    const int s_row = t >> 2;
    const int s_kof = (t & 3) << 3;

    for (int k0 = 0; k0 < K; k0 += 32) {
#pragma unroll
        for (int it = 0; it < 2; ++it) {
            const int idx = it * 256 + t;
            const int row = it * 64 + s_row;
            gld_lds16(Abase + (size_t)row * lda + k0 + s_kof, As + idx * 8);
            gld_lds16(Bbase + (size_t)row * ldb + k0 + s_kof, Bs + idx * 8);
        }
        __syncthreads();

        bf16x8 af[4], bf[4];
#pragma unroll
        for (int i = 0; i < 4; ++i) {
            af[i] = *(const bf16x8*)(As + ((wr * 64 + i * 16 + (lane & 15)) * 32 + (lane >> 4) * 8));
            bf[i] = *(const bf16x8*)(Bs + ((wc * 64 + i * 16 + (lane & 15)) * 32 + (lane >> 4) * 8));
        }
#pragma unroll
        for (int i = 0; i < 4; ++i)
#pragma unroll
            for (int j = 0; j < 4; ++j)
                acc[i][j] = __builtin_amdgcn_mfma_f32_16x16x32_bf16(
                    af[i], bf[j], acc[i][j], 0, 0, 0);
        __syncthreads();
    }

    // --- epilogue: acc -> LDS (bf16) -> coalesced uint4 stores ---
    const int col   = lane & 15;
    const int rquad = (lane >> 4) * 4;
#pragma unroll
    for (int j = 0; j < 4; ++j) {
        const int lc = wc * 64 + j * 16 + col;
        const float bv = bias ? bias[n0 + lc] : 0.0f;
#pragma unroll
        for (int i = 0; i < 4; ++i) {
            const int lr0 = wr * 64 + i * 16 + rquad;
#pragma unroll
            for (int r = 0; r < 4; ++r) {
                float v = acc[i][j][r] * scale + bv;
                if (relu) v = fmaxf(v, 0.0f);
                smem[(lr0 + r) * EPW + lc] = f2bf(v);
            }
        }
    }
    __syncthreads();

    const int cr = t >> 4;          // 0..15
    const int cc = t & 15;          // 0..15, 8-short chunks
#pragma unroll
    for (int rr = 0; rr < 8; ++rr) {
        const int row = rr * 16 + cr;
        uint4 v = *(const uint4*)(smem + row * EPW + cc * 8);
        *(uint4*)(C + (m0 + row) * (size_t)ldc + n0 + cc * 8) = v;
    }
}

// ---------- elementwise fp32 -> bf16 cast -----------------------------------
__global__ __launch_bounds__(256) void cast_bf16_kernel(
    const float* __restrict__ in, unsigned short* __restrict__ out, int n4)
{
    const int i = blockIdx.x * 256 + threadIdx.x;
    if (i < n4) {
        float4 v = *(const float4*)(in + (size_t)i * 4);
        ushort4 o;
        o.x = f2bf(v.x); o.y = f2bf(v.y); o.z = f2bf(v.z); o.w = f2bf(v.w);
        *(ushort4*)(out + (size_t)i * 4) = o;
    }
}

// ---------- transpose + cast: W[K,N] fp32 -> WT[N,K] bf16 -------------------
__global__ __launch_bounds__(256) void transpose_cast_kernel(
    const float* __restrict__ W, unsigned short* __restrict__ WT, int K, int N)
{
    __shared__ float tile[32][33];
    const int k0 = blockIdx.y * 32;
    const int n0 = blockIdx.x * 32;
    const int tr = threadIdx.x >> 3;
    const int tc = (threadIdx.x & 7) * 4;

    float4 v = *(const float4*)(W + (size_t)(k0 + tr) * N + n0 + tc);
    tile[tr][tc + 0] = v.x;
    tile[tr][tc + 1] = v.y;
    tile[tr][tc + 2] = v.z;
    tile[tr][tc + 3] = v.w;
    __syncthreads();

    ushort4 o;
    o.x = f2bf(tile[tc + 0][tr]);
    o.y = f2bf(tile[tc + 1][tr]);
    o.z = f2bf(tile[tc + 2][tr]);
    o.w = f2bf(tile[tc + 3][tr]);
    *(ushort4*)(WT + (size_t)(n0 + tr) * K + k0 + tc) = o;
}

// ---------- row L2-normalize, bf16 in-place, width 512 ----------------------
__global__ __launch_bounds__(128) void normalize_bf16_kernel(
    unsigned short* __restrict__ X)
{
    const int r = blockIdx.x;
    const int t = threadIdx.x;
    unsigned short* row = X + (size_t)r * 512;
    ushort4 u = *(const ushort4*)(row + t * 4);
    float x0 = bf2f(u.x), x1 = bf2f(u.y), x2 = bf2f(u.z), x3 = bf2f(u.w);
    float ss = x0 * x0 + x1 * x1 + x2 * x2 + x3 * x3;
#pragma unroll
    for (int off = 32; off > 0; off >>= 1) ss += __shfl_down(ss, off, 64);
    __shared__ float sred[2];
    if ((t & 63) == 0) sred[t >> 6] = ss;
    __syncthreads();
    float inv = 1.0f / sqrtf(sred[0] + sred[1]);
    ushort4 o;
    o.x = f2bf(x0 * inv); o.y = f2bf(x1 * inv);
    o.z = f2bf(x2 * inv); o.w = f2bf(x3 * inv);
    *(ushort4*)(row + t * 4) = o;
}

// ---------- per-row mining + loss (v3) --------------------------------------
// 512 threads/block, one block per row. S row bf16, read twice from global
// (L2/L3-hot). Single 12-bit radix pass, shuffle suffix scan, fixed bmax=16.
__global__ __launch_bounds__(512) void row_loss_kernel(
    const unsigned short* __restrict__ S, int row_base,
    const float* __restrict__ mw, int midx, float* __restrict__ accum)
{
    __shared__ unsigned hist[4096];         // 16 KB
    __shared__ unsigned wtot[8];
    __shared__ float fred[8];
    __shared__ unsigned sh_b;
    __shared__ float sh_diag;

    const int t    = threadIdx.x;
    const int lane = t & 63;
    const int wv   = t >> 6;
    const int i    = row_base + blockIdx.x;     // diag column index
    const unsigned short* Srow = S + (size_t)blockIdx.x * 8192;

    for (int b = t; b < 4096; b += 512) hist[b] = 0;
    __syncthreads();

    // pass A: histogram (vectorized, 2 x uint4 = 16 elems/thread)
    for (int base = t * 8; base < 8192; base += 4096) {
        uint4 raw = *(const uint4*)(Srow + base);
        const unsigned short* e = (const unsigned short*)&raw;
#pragma unroll
        for (int q = 0; q < 8; ++q) {
            const int j = base + q;
            float s = bf2f(e[q]);
            if (j != i && s <= 9.0f) {
                int k = (int)((s + 10.25f) * 200.0f);
                k = k < 1 ? 1 : (k > 4095 ? 4095 : k);
                atomicAdd(&hist[k], 1u);
            }
        }
    }
    __syncthreads();

    // suffix scan: thread owns buckets [t*8, t*8+8)
    unsigned local = 0;
#pragma unroll
    for (int q = 0; q < 8; ++q) local += hist[t * 8 + q];
    unsigned suf = local;
#pragma unroll
    for (int off = 1; off < 64; off <<= 1) {
        unsigned v = __shfl_down(suf, off, 64);
        if (lane + off < 64) suf += v;
    }
    if (lane == 0) wtot[wv] = suf;
    __syncthreads();
    unsigned wsuf = 0;
#pragma unroll
    for (int q = 0; q < 8; ++q) wsuf += (q > wv) ? wtot[q] : 0u;
    suf += wsuf;

    const unsigned target = 4096;
    const unsigned above  = suf - local;
    if (suf >= target && above < target) {
        unsigned cum = above;
        int bsel = t * 8;
#pragma unroll
        for (int q = 7; q >= 0; --q) {
            unsigned c = hist[t * 8 + q];
            if (cum + c >= target) { bsel = t * 8 + q; break; }
            cum += c;
        }
        sh_b = (unsigned)bsel;
    }
    if (t == 0 && suf < target) sh_b = 1u;
    __syncthreads();
    const unsigned bsel = sh_b;

    // pass B: weighted exp-sum with fixed bmax = 16
    float lsum = 0.0f;
    for (int base = t * 8; base < 8192; base += 4096) {
        uint4 raw = *(const uint4*)(Srow + base);
        const unsigned short* e = (const unsigned short*)&raw;
#pragma unroll
        for (int q = 0; q < 8; ++q) {
            const int j = base + q;
            float s = bf2f(e[q]);
            bool diag  = (j == i);
            bool noise = (!diag && s > 9.0f);
            int k = (int)((s + 10.25f) * 200.0f);
            k = k < 1 ? 1 : (k > 4095 ? 4095 : k);
            bool hard = !diag && !noise && ((unsigned)k >= bsel);
            float wgt = noise ? 0.5f : (hard ? 1.5f : 1.0f);
            float ws = s * wgt;
            if (diag) sh_diag = ws;
            lsum += __expf(ws - 16.0f);
        }
    }
#pragma unroll
    for (int off = 32; off > 0; off >>= 1)
        lsum += __shfl_down(lsum, off, 64);
    if (lane == 0) fred[wv] = lsum;
    __syncthreads();
    if (t == 0) {
        float total = 0.0f;
#pragma unroll
        for (int q = 0; q < 8; ++q) total += fred[q];
        float lse = 16.0f + logf(total);
        float ce = lse - sh_diag;
        atomicAdd(&accum[midx], ce * mw[(size_t)i * 2 + midx]);
    }
}

__global__ void zero_kernel(float* __restrict__ accum)
{
    if (threadIdx.x < 2) accum[threadIdx.x] = 0.0f;
}

__global__ void finalize_kernel(const float* __restrict__ accum,
                                float* __restrict__ out)
{
    out[0] = (accum[0] + accum[1]) * (1.0f / 16384.0f);
}

// ---------------------------------------------------------------------------
extern "C" void kernel_launch(void* const* d_in, const int* in_sizes, int n_in,
                              void* d_out, int out_size, void* d_ws, size_t ws_size,
                              hipStream_t stream)
{
    (void)in_sizes; (void)n_in; (void)out_size; (void)ws_size;

    const float* id_emb = (const float*)d_in[0];
    const float* feats[2] = { (const float*)d_in[1], (const float*)d_in[2] };
    const float* mw     = (const float*)d_in[3];
    const float* Wa[2]  = { (const float*)d_in[4],  (const float*)d_in[6]  };
    const float* ba[2]  = { (const float*)d_in[5],  (const float*)d_in[7]  };
    const float* W1[2]  = { (const float*)d_in[8],  (const float*)d_in[12] };
    const float* b1[2]  = { (const float*)d_in[9],  (const float*)d_in[13] };
    const float* W2[2]  = { (const float*)d_in[10], (const float*)d_in[14] };
    const float* b2[2]  = { (const float*)d_in[11], (const float*)d_in[15] };
    const int    Fdim[2] = { 768, 2048 };

    char* p = (char*)d_ws;
    unsigned short* WaT   = (unsigned short*)p; p += (size_t)1024 * 2048 * 2;  //  4 MB
    unsigned short* W1T   = (unsigned short*)p; p += (size_t)1024 * 1024 * 2;  //  2 MB
    unsigned short* W2T   = (unsigned short*)p; p += (size_t)512  * 1024 * 2;  //  1 MB
    unsigned short* featb = (unsigned short*)p; p += (size_t)8192 * 2048 * 2;  // 32 MB
    unsigned short* X     = (unsigned short*)p; p += (size_t)16384 * 1024 * 2; // 32 MB
    unsigned short* H     = (unsigned short*)p; p += (size_t)16384 * 1024 * 2; // 32 MB
    unsigned short* PB    = (unsigned short*)p; p += (size_t)16384 * 512  * 2; // 16 MB
    float*          accum = (float*)p;
    unsigned short* S     = X;                   // 4096x8192 bf16 = 64 MB (X+H)

    zero_kernel<<<1, 64, 0, stream>>>(accum);

    for (int m = 0; m < 2; ++m) {
        const int F = Fdim[m];

        cast_bf16_kernel<<<(8192 * F / 4 + 255) / 256, 256, 0, stream>>>(
            feats[m], featb, 8192 * F / 4);
        transpose_cast_kernel<<<dim3(1024 / 32, F / 32), 256, 0, stream>>>(
            Wa[m], WaT, F, 1024);
        transpose_cast_kernel<<<dim3(1024 / 32, 1024 / 32), 256, 0, stream>>>(
            W1[m], W1T, 1024, 1024);
        transpose_cast_kernel<<<dim3(512 / 32, 1024 / 32), 256, 0, stream>>>(
            W2[m], W2T, 1024, 512);

        // X[0:8192]  = feat @ Wa + ba  (bf16)
        gemm_bt_mfma<<<(8192 / 128) * (1024 / 128), 256, 0, stream>>>(
            featb, F, WaT, F, X, 1024, 8192, 1024, F, ba[m], 0, 1.0f);
        // X[8192:]   = id (bf16 cast)
        cast_bf16_kernel<<<(8192 * 1024 / 4 + 255) / 256, 256, 0, stream>>>(
            id_emb, X + (size_t)8192 * 1024, 8192 * 1024 / 4);

        // H = relu(X @ W1 + b1)        (16384 x 1024, bf16)
        gemm_bt_mfma<<<(16384 / 128) * (1024 / 128), 256, 0, stream>>>(
            X, 1024, W1T, 1024, H, 1024, 16384, 1024, 1024, b1[m], 1, 1.0f);
        // PB = H @ W2 + b2             (16384 x 512, bf16)
        gemm_bt_mfma<<<(16384 / 128) * (512 / 128), 256, 0, stream>>>(
            H, 1024, W2T, 1024, PB, 512, 16384, 512, 1024, b2[m], 0, 1.0f);
        // normalize in place           (modal rows 0:8192, id rows 8192:)
        normalize_bf16_kernel<<<16384, 128, 0, stream>>>(PB);

        const unsigned short* mproj = PB;
        const unsigned short* iproj = PB + (size_t)8192 * 512;

        for (int c = 0; c < 2; ++c) {
            // S = 10 * id_proj[chunk 4096] @ modal_proj^T  (4096 x 8192 bf16)
            gemm_bt_mfma<<<(4096 / 128) * (8192 / 128), 256, 0, stream>>>(
                iproj + (size_t)c * 4096 * 512, 512, mproj, 512,
                S, 8192, 4096, 8192, 512, nullptr, 0, 10.0f);
            row_loss_kernel<<<4096, 512, 0, stream>>>(
                S, c * 4096, mw, m, accum);
        }
    }

    finalize_kernel<<<1, 1, 0, stream>>>(accum, (float*)d_out);
}

// Round 7
// 878.343 us; speedup vs baseline: 7.3601x; 1.0530x over previous
//
#include <hip/hip_runtime.h>
#include <math.h>
#include <stdint.h>

// ---------------------------------------------------------------------------
// IntraModalContrastive loss. Round 6:
//  - GEMM: 256x128 tile, 512 threads (8 waves, 4x2), BK=32. Staging 24 KB/iter
//    feeds 128 wave-MFMAs (1.33x better compute:staging vs 128x128).
//  - Epilogue: two 128-row half-passes through 34816 B LDS, coalesced stores.
//  - id cast hoisted out of the modality loop (S aliases featb+H, X persists).
// ---------------------------------------------------------------------------

typedef __attribute__((ext_vector_type(4))) float  floatx4;
typedef __attribute__((ext_vector_type(8))) __bf16 bf16x8;

__device__ __forceinline__ unsigned short f2bf(float f)
{
    unsigned u = __float_as_uint(f);
    unsigned r = (u + 0x7FFFu + ((u >> 16) & 1u)) >> 16;
    return (unsigned short)r;
}

__device__ __forceinline__ float bf2f(unsigned short u)
{
    return __uint_as_float((unsigned)u << 16);
}

__device__ __forceinline__ void gld_lds16(const void* g, void* l)
{
    __builtin_amdgcn_global_load_lds(
        (const __attribute__((address_space(1))) void*)g,
        (__attribute__((address_space(3))) void*)(uint32_t)(uintptr_t)l,
        16, 0, 0);
}

#define EPW 136   // epilogue LDS row stride in shorts (272 B, 16B-aligned)

// ---------- bf16 MFMA GEMM: 256x128 tile, 512 thr, BK=32 --------------------
// C[M,N] = ep(scale*(A @ B^T) + bias); A: MxK bf16 (lda), B: NxK bf16 (ldb).
// grid.x == (M/256)*(N/128), divisible by 8; M/256 divisible by 4.
__global__ __launch_bounds__(512) void gemm_bt_mfma(
    const unsigned short* __restrict__ A, int lda,
    const unsigned short* __restrict__ B, int ldb,
    unsigned short* __restrict__ C, int ldc, int M, int N, int K,
    const float* __restrict__ bias, int relu, float scale)
{
    // union: K-loop As(256x32)+Bs(128x32) = 12288 shorts; epilogue 128xEPW
    __shared__ __align__(16) unsigned short smem[128 * EPW];   // 34816 B
    unsigned short* As = smem;
    unsigned short* Bs = smem + 8192;

    const int num_n = N >> 7;
    const int per   = gridDim.x >> 3;
    const int pid   = blockIdx.x;
    const int npid  = (pid & 7) * per + (pid >> 3);
    const int width = 4 * num_n;
    const int group = npid / width;
    const int rem   = npid - group * width;
    const int pm    = group * 4 + (rem & 3);
    const int pn    = rem >> 2;

    const int t    = threadIdx.x;
    const int lane = t & 63;
    const int w    = t >> 6;        // 0..7
    const int wr   = w >> 1;        // 0..3 (64-row band)
    const int wc   = w & 1;         // 0..1 (64-col band)
    const size_t m0 = (size_t)pm * 256;
    const size_t n0 = (size_t)pn * 128;

    floatx4 acc[4][4] = {};

    const unsigned short* Abase = A + m0 * (size_t)lda;
    const unsigned short* Bbase = B + n0 * (size_t)ldb;

    const int s_row = t >> 2;            // 0..127
    const int s_kof = (t & 3) << 3;      // 0,8,16,24

    for (int k0 = 0; k0 < K; k0 += 32) {
#pragma unroll
        for (int it = 0; it < 2; ++it) {
            const int row = it * 128 + s_row;
            gld_lds16(Abase + (size_t)row * lda + k0 + s_kof,
                      As + (it * 512 + t) * 8);
        }
        gld_lds16(Bbase + (size_t)s_row * ldb + k0 + s_kof, Bs + t * 8);
        __syncthreads();

        bf16x8 af[4], bf[4];
#pragma unroll
        for (int i = 0; i < 4; ++i) {
            af[i] = *(const bf16x8*)(As + ((wr * 64 + i * 16 + (lane & 15)) * 32 + (lane >> 4) * 8));
            bf[i] = *(const bf16x8*)(Bs + ((wc * 64 + i * 16 + (lane & 15)) * 32 + (lane >> 4) * 8));
        }
#pragma unroll
        for (int i = 0; i < 4; ++i)
#pragma unroll
            for (int j = 0; j < 4; ++j)
                acc[i][j] = __builtin_amdgcn_mfma_f32_16x16x32_bf16(
                    af[i], bf[j], acc[i][j], 0, 0, 0);
        __syncthreads();
    }

    // --- epilogue: two 128-row halves through LDS, coalesced uint4 stores ---
    const int col   = lane & 15;
    const int rquad = (lane >> 4) * 4;
#pragma unroll
    for (int h = 0; h < 2; ++h) {
        if ((wr >> 1) == h) {
#pragma unroll
            for (int j = 0; j < 4; ++j) {
                const int lc = wc * 64 + j * 16 + col;
                const float bv = bias ? bias[n0 + lc] : 0.0f;
#pragma unroll
                for (int i = 0; i < 4; ++i) {
                    const int lr0 = (wr & 1) * 64 + i * 16 + rquad;
#pragma unroll
                    for (int r = 0; r < 4; ++r) {
                        float v = acc[i][j][r] * scale + bv;
                        if (relu) v = fmaxf(v, 0.0f);
                        smem[(lr0 + r) * EPW + lc] = f2bf(v);
                    }
                }
            }
        }
        __syncthreads();
        const int cr = t >> 2;          // 0..127
        const int cq = t & 3;
#pragma unroll
        for (int q = 0; q < 4; ++q) {
            const int chunk = cq + q * 4;           // 0..15
            uint4 v = *(const uint4*)(smem + cr * EPW + chunk * 8);
            *(uint4*)(C + (m0 + h * 128 + cr) * (size_t)ldc + n0 + chunk * 8) = v;
        }
        __syncthreads();
    }
}

// ---------- elementwise fp32 -> bf16 cast -----------------------------------
__global__ __launch_bounds__(256) void cast_bf16_kernel(
    const float* __restrict__ in, unsigned short* __restrict__ out, int n4)
{
    const int i = blockIdx.x * 256 + threadIdx.x;
    if (i < n4) {
        float4 v = *(const float4*)(in + (size_t)i * 4);
        ushort4 o;
        o.x = f2bf(v.x); o.y = f2bf(v.y); o.z = f2bf(v.z); o.w = f2bf(v.w);
        *(ushort4*)(out + (size_t)i * 4) = o;
    }
}

// ---------- transpose + cast: W[K,N] fp32 -> WT[N,K] bf16 -------------------
__global__ __launch_bounds__(256) void transpose_cast_kernel(
    const float* __restrict__ W, unsigned short* __restrict__ WT, int K, int N)
{
    __shared__ float tile[32][33];
    const int k0 = blockIdx.y * 32;
    const int n0 = blockIdx.x * 32;
    const int tr = threadIdx.x >> 3;
    const int tc = (threadIdx.x & 7) * 4;

    float4 v = *(const float4*)(W + (size_t)(k0 + tr) * N + n0 + tc);
    tile[tr][tc + 0] = v.x;
    tile[tr][tc + 1] = v.y;
    tile[tr][tc + 2] = v.z;
    tile[tr][tc + 3] = v.w;
    __syncthreads();

    ushort4 o;
    o.x = f2bf(tile[tc + 0][tr]);
    o.y = f2bf(tile[tc + 1][tr]);
    o.z = f2bf(tile[tc + 2][tr]);
    o.w = f2bf(tile[tc + 3][tr]);
    *(ushort4*)(WT + (size_t)(n0 + tr) * K + k0 + tc) = o;
}

// ---------- row L2-normalize, bf16 in-place, width 512 ----------------------
__global__ __launch_bounds__(128) void normalize_bf16_kernel(
    unsigned short* __restrict__ X)
{
    const int r = blockIdx.x;
    const int t = threadIdx.x;
    unsigned short* row = X + (size_t)r * 512;
    ushort4 u = *(const ushort4*)(row + t * 4);
    float x0 = bf2f(u.x), x1 = bf2f(u.y), x2 = bf2f(u.z), x3 = bf2f(u.w);
    float ss = x0 * x0 + x1 * x1 + x2 * x2 + x3 * x3;
#pragma unroll
    for (int off = 32; off > 0; off >>= 1) ss += __shfl_down(ss, off, 64);
    __shared__ float sred[2];
    if ((t & 63) == 0) sred[t >> 6] = ss;
    __syncthreads();
    float inv = 1.0f / sqrtf(sred[0] + sred[1]);
    ushort4 o;
    o.x = f2bf(x0 * inv); o.y = f2bf(x1 * inv);
    o.z = f2bf(x2 * inv); o.w = f2bf(x3 * inv);
    *(ushort4*)(row + t * 4) = o;
}

// ---------- per-row mining + loss (v3) --------------------------------------
__global__ __launch_bounds__(512) void row_loss_kernel(
    const unsigned short* __restrict__ S, int row_base,
    const float* __restrict__ mw, int midx, float* __restrict__ accum)
{
    __shared__ unsigned hist[4096];         // 16 KB
    __shared__ unsigned wtot[8];
    __shared__ float fred[8];
    __shared__ unsigned sh_b;
    __shared__ float sh_diag;

    const int t    = threadIdx.x;
    const int lane = t & 63;
    const int wv   = t >> 6;
    const int i    = row_base + blockIdx.x;     // diag column index
    const unsigned short* Srow = S + (size_t)blockIdx.x * 8192;

    for (int b = t; b < 4096; b += 512) hist[b] = 0;
    __syncthreads();

    for (int base = t * 8; base < 8192; base += 4096) {
        uint4 raw = *(const uint4*)(Srow + base);
        const unsigned short* e = (const unsigned short*)&raw;
#pragma unroll
        for (int q = 0; q < 8; ++q) {
            const int j = base + q;
            float s = bf2f(e[q]);
            if (j != i && s <= 9.0f) {
                int k = (int)((s + 10.25f) * 200.0f);
                k = k < 1 ? 1 : (k > 4095 ? 4095 : k);
                atomicAdd(&hist[k], 1u);
            }
        }
    }
    __syncthreads();

    unsigned local = 0;
#pragma unroll
    for (int q = 0; q < 8; ++q) local += hist[t * 8 + q];
    unsigned suf = local;
#pragma unroll
    for (int off = 1; off < 64; off <<= 1) {
        unsigned v = __shfl_down(suf, off, 64);
        if (lane + off < 64) suf += v;
    }
    if (lane == 0) wtot[wv] = suf;
    __syncthreads();
    unsigned wsuf = 0;
#pragma unroll
    for (int q = 0; q < 8; ++q) wsuf += (q > wv) ? wtot[q] : 0u;
    suf += wsuf;

    const unsigned target = 4096;
    const unsigned above  = suf - local;
    if (suf >= target && above < target) {
        unsigned cum = above;
        int bsel = t * 8;
#pragma unroll
        for (int q = 7; q >= 0; --q) {
            unsigned c = hist[t * 8 + q];
            if (cum + c >= target) { bsel = t * 8 + q; break; }
            cum += c;
        }
        sh_b = (unsigned)bsel;
    }
    if (t == 0 && suf < target) sh_b = 1u;
    __syncthreads();
    const unsigned bsel = sh_b;

    float lsum = 0.0f;
    for (int base = t * 8; base < 8192; base += 4096) {
        uint4 raw = *(const uint4*)(Srow + base);
        const unsigned short* e = (const unsigned short*)&raw;
#pragma unroll
        for (int q = 0; q < 8; ++q) {
            const int j = base + q;
            float s = bf2f(e[q]);
            bool diag  = (j == i);
            bool noise = (!diag && s > 9.0f);
            int k = (int)((s + 10.25f) * 200.0f);
            k = k < 1 ? 1 : (k > 4095 ? 4095 : k);
            bool hard = !diag && !noise && ((unsigned)k >= bsel);
            float wgt = noise ? 0.5f : (hard ? 1.5f : 1.0f);
            float ws = s * wgt;
            if (diag) sh_diag = ws;
            lsum += __expf(ws - 16.0f);
        }
    }
#pragma unroll
    for (int off = 32; off > 0; off >>= 1)
        lsum += __shfl_down(lsum, off, 64);
    if (lane == 0) fred[wv] = lsum;
    __syncthreads();
    if (t == 0) {
        float total = 0.0f;
#pragma unroll
        for (int q = 0; q < 8; ++q) total += fred[q];
        float lse = 16.0f + logf(total);
        float ce = lse - sh_diag;
        atomicAdd(&accum[midx], ce * mw[(size_t)i * 2 + midx]);
    }
}

__global__ void zero_kernel(float* __restrict__ accum)
{
    if (threadIdx.x < 2) accum[threadIdx.x] = 0.0f;
}

__global__ void finalize_kernel(const float* __restrict__ accum,
                                float* __restrict__ out)
{
    out[0] = (accum[0] + accum[1]) * (1.0f / 16384.0f);
}

// ---------------------------------------------------------------------------
extern "C" void kernel_launch(void* const* d_in, const int* in_sizes, int n_in,
                              void* d_out, int out_size, void* d_ws, size_t ws_size,
                              hipStream_t stream)
{
    (void)in_sizes; (void)n_in; (void)out_size; (void)ws_size;

    const float* id_emb = (const float*)d_in[0];
    const float* feats[2] = { (const float*)d_in[1], (const float*)d_in[2] };
    const float* mw     = (const float*)d_in[3];
    const float* Wa[2]  = { (const float*)d_in[4],  (const float*)d_in[6]  };
    const float* ba[2]  = { (const float*)d_in[5],  (const float*)d_in[7]  };
    const float* W1[2]  = { (const float*)d_in[8],  (const float*)d_in[12] };
    const float* b1[2]  = { (const float*)d_in[9],  (const float*)d_in[13] };
    const float* W2[2]  = { (const float*)d_in[10], (const float*)d_in[14] };
    const float* b2[2]  = { (const float*)d_in[11], (const float*)d_in[15] };
    const int    Fdim[2] = { 768, 2048 };

    // Layout: X is NOT aliased (id half persists across modalities);
    // S (64 MB) aliases featb+H (both dead during the sim phase).
    char* p = (char*)d_ws;
    unsigned short* WaT   = (unsigned short*)p; p += (size_t)1024 * 2048 * 2;  //  4 MB
    unsigned short* W1T   = (unsigned short*)p; p += (size_t)1024 * 1024 * 2;  //  2 MB
    unsigned short* W2T   = (unsigned short*)p; p += (size_t)512  * 1024 * 2;  //  1 MB
    unsigned short* X     = (unsigned short*)p; p += (size_t)16384 * 1024 * 2; // 32 MB
    unsigned short* featb = (unsigned short*)p; p += (size_t)8192 * 2048 * 2;  // 32 MB
    unsigned short* H     = (unsigned short*)p; p += (size_t)16384 * 1024 * 2; // 32 MB
    unsigned short* PB    = (unsigned short*)p; p += (size_t)16384 * 512  * 2; // 16 MB
    float*          accum = (float*)p;
    unsigned short* S     = featb;               // 4096x8192 bf16 = 64 MB

    zero_kernel<<<1, 64, 0, stream>>>(accum);

    // id embeddings -> bf16 lower half of X, once (X never aliased)
    cast_bf16_kernel<<<(8192 * 1024 / 4 + 255) / 256, 256, 0, stream>>>(
        id_emb, X + (size_t)8192 * 1024, 8192 * 1024 / 4);

    for (int m = 0; m < 2; ++m) {
        const int F = Fdim[m];

        cast_bf16_kernel<<<(8192 * F / 4 + 255) / 256, 256, 0, stream>>>(
            feats[m], featb, 8192 * F / 4);
        transpose_cast_kernel<<<dim3(1024 / 32, F / 32), 256, 0, stream>>>(
            Wa[m], WaT, F, 1024);
        transpose_cast_kernel<<<dim3(1024 / 32, 1024 / 32), 256, 0, stream>>>(
            W1[m], W1T, 1024, 1024);
        transpose_cast_kernel<<<dim3(512 / 32, 1024 / 32), 256, 0, stream>>>(
            W2[m], W2T, 1024, 512);

        // X[0:8192] = feat @ Wa + ba   (8192 x 1024, bf16)
        gemm_bt_mfma<<<(8192 / 256) * (1024 / 128), 512, 0, stream>>>(
            featb, F, WaT, F, X, 1024, 8192, 1024, F, ba[m], 0, 1.0f);

        // H = relu(X @ W1 + b1)        (16384 x 1024, bf16)
        gemm_bt_mfma<<<(16384 / 256) * (1024 / 128), 512, 0, stream>>>(
            X, 1024, W1T, 1024, H, 1024, 16384, 1024, 1024, b1[m], 1, 1.0f);
        // PB = H @ W2 + b2             (16384 x 512, bf16)
        gemm_bt_mfma<<<(16384 / 256) * (512 / 128), 512, 0, stream>>>(
            H, 1024, W2T, 1024, PB, 512, 16384, 512, 1024, b2[m], 0, 1.0f);
        // normalize in place           (modal rows 0:8192, id rows 8192:)
        normalize_bf16_kernel<<<16384, 128, 0, stream>>>(PB);

        const unsigned short* mproj = PB;
        const unsigned short* iproj = PB + (size_t)8192 * 512;

        for (int c = 0; c < 2; ++c) {
            // S = 10 * id_proj[chunk 4096] @ modal_proj^T  (4096 x 8192 bf16)
            gemm_bt_mfma<<<(4096 / 256) * (8192 / 128), 512, 0, stream>>>(
                iproj + (size_t)c * 4096 * 512, 512, mproj, 512,
                S, 8192, 4096, 8192, 512, nullptr, 0, 10.0f);
            row_loss_kernel<<<4096, 512, 0, stream>>>(
                S, c * 4096, mw, m, accum);
        }
    }

    finalize_kernel<<<1, 1, 0, stream>>>(accum, (float*)d_out);
}